// Round 1
// baseline (2278.336 us; speedup 1.0000x reference)
//
#include <hip/hip_runtime.h>
#include <hip/hip_bf16.h>
#include <math.h>

#define N_NODES 50000
#define N_EDGES 850000
#define IN_DIM  256
#define HD      128      // H1*D
#define H1      4
#define D       32
#define NC      40       // num classes
#define SLOPE   0.2f
#define EPS_BN  1e-5f

// ---------------------------------------------------------------------------
// fp32 tiled SGEMM: C = A(MxK) @ B(KxN). 64x64 tile, BK=16, 256 thr, 4x4/thread
// ---------------------------------------------------------------------------
__global__ __launch_bounds__(256) void sgemm_k(const float* __restrict__ A,
                                               const float* __restrict__ B,
                                               float* __restrict__ Cm,
                                               int M, int N, int K) {
    __shared__ float As[16][68];   // transposed, +4 pad
    __shared__ float Bs[16][64];
    int tid = threadIdx.x;
    int tx = tid & 15, ty = tid >> 4;
    int rowBase = blockIdx.y * 64, colBase = blockIdx.x * 64;
    int arow = tid >> 2, akk = (tid & 3) << 2;     // A: 64 rows x 16 k, float4 on k
    int brow = tid >> 4, bcol = (tid & 15) << 2;   // B: 16 k x 64 cols, float4 on col
    float acc[4][4] = {};
    for (int k0 = 0; k0 < K; k0 += 16) {
        float4 av = make_float4(0.f, 0.f, 0.f, 0.f);
        int gr = rowBase + arow;
        if (gr < M) av = *(const float4*)(A + (size_t)gr * K + k0 + akk);
        As[akk + 0][arow] = av.x; As[akk + 1][arow] = av.y;
        As[akk + 2][arow] = av.z; As[akk + 3][arow] = av.w;
        float4 bv = make_float4(0.f, 0.f, 0.f, 0.f);
        int gc = colBase + bcol;
        if (gc + 3 < N) bv = *(const float4*)(B + (size_t)(k0 + brow) * N + gc);
        *(float4*)(&Bs[brow][bcol]) = bv;
        __syncthreads();
        #pragma unroll
        for (int k = 0; k < 16; ++k) {
            float a[4], b[4];
            #pragma unroll
            for (int i = 0; i < 4; ++i) a[i] = As[k][ty * 4 + i];
            #pragma unroll
            for (int j = 0; j < 4; ++j) b[j] = Bs[k][tx * 4 + j];
            #pragma unroll
            for (int i = 0; i < 4; ++i)
                #pragma unroll
                for (int j = 0; j < 4; ++j)
                    acc[i][j] = fmaf(a[i], b[j], acc[i][j]);
        }
        __syncthreads();
    }
    #pragma unroll
    for (int i = 0; i < 4; ++i) {
        int r = rowBase + ty * 4 + i;
        if (r >= M) continue;
        #pragma unroll
        for (int j = 0; j < 4; ++j) {
            int c = colBase + tx * 4 + j;
            if (c < N) Cm[(size_t)r * N + c] = acc[i][j];
        }
    }
}

// ---------------------------------------------------------------------------
// el/er for layer 1: one thread per (node, head); reads 32 floats of ft row
// ---------------------------------------------------------------------------
__global__ void eler1_k(const float* __restrict__ ft,
                        const float* __restrict__ al, const float* __restrict__ ar,
                        float* __restrict__ el, float* __restrict__ er) {
    int t = blockIdx.x * blockDim.x + threadIdx.x;
    if (t >= N_NODES * H1) return;
    int n = t >> 2, h = t & 3;
    const float* f = ft + (size_t)n * HD + h * D;
    const float* a = al + h * D;
    const float* r = ar + h * D;
    float sl = 0.f, sr = 0.f;
    #pragma unroll
    for (int d = 0; d < D; d += 4) {
        float4 fv = *(const float4*)(f + d);
        float4 av = *(const float4*)(a + d);
        float4 rv = *(const float4*)(r + d);
        sl += fv.x * av.x + fv.y * av.y + fv.z * av.z + fv.w * av.w;
        sr += fv.x * rv.x + fv.y * rv.y + fv.z * rv.z + fv.w * rv.w;
    }
    el[t] = sl; er[t] = sr;
}

// ---------------------------------------------------------------------------
// layer-1 edge aggregation: 32 lanes per edge, lane owns 4 dims (one head per
// 8 lanes). agg[dst] += exp(leaky(el[src]+er[dst])) * ft[src]; s[dst] += exp.
// (segment-max skipped: |e| <= ~8 here, softmax is shift-invariant)
// ---------------------------------------------------------------------------
__global__ void edge_agg1_k(const int* __restrict__ src, const int* __restrict__ dst,
                            const float* __restrict__ ft,
                            const float* __restrict__ el, const float* __restrict__ er,
                            float* __restrict__ agg, float* __restrict__ s) {
    int gid = blockIdx.x * blockDim.x + threadIdx.x;
    int eid = gid >> 5;
    if (eid >= N_EDGES) return;
    int lane = gid & 31;
    int u = src[eid], v = dst[eid];
    int h = lane >> 3;
    float e = el[u * H1 + h] + er[v * H1 + h];
    e = e > 0.f ? e : SLOPE * e;
    float ex = __expf(e);
    if ((lane & 7) == 0) atomicAdd(&s[v * H1 + h], ex);
    float4 f = *(const float4*)(ft + (size_t)u * HD + lane * 4);
    float* out = agg + (size_t)v * HD + lane * 4;
    atomicAdd(out + 0, ex * f.x);
    atomicAdd(out + 1, ex * f.y);
    atomicAdd(out + 2, ex * f.z);
    atomicAdd(out + 3, ex * f.w);
}

// s -> 1/max(s,1e-9), in place
__global__ void rcp_k(float* __restrict__ s, int n) {
    int t = blockIdx.x * blockDim.x + threadIdx.x;
    if (t < n) s[t] = 1.0f / fmaxf(s[t], 1e-9f);
}

// ---------------------------------------------------------------------------
// BN stats: per-feature sum & sumsq of h = agg * sinv  (128 features)
// ---------------------------------------------------------------------------
__global__ void bnstats_k(const float* __restrict__ agg, const float* __restrict__ sinv,
                          float* __restrict__ sums, float* __restrict__ sumsq) {
    int c = threadIdx.x;  // 128 threads
    float acc = 0.f, acc2 = 0.f;
    for (int r = blockIdx.x; r < N_NODES; r += gridDim.x) {
        float v = agg[(size_t)r * HD + c] * sinv[r * H1 + (c >> 5)];
        acc += v; acc2 += v * v;
    }
    atomicAdd(&sums[c], acc);
    atomicAdd(&sumsq[c], acc2);
}

// ---------------------------------------------------------------------------
// BN apply + ELU: out = elu((agg*sinv - mu)*rsqrt(var+eps)*gamma + beta)
// ---------------------------------------------------------------------------
__global__ void bnapply_k(const float* __restrict__ agg, const float* __restrict__ sinv,
                          const float* __restrict__ sums, const float* __restrict__ sumsq,
                          const float* __restrict__ gamma, const float* __restrict__ beta,
                          float* __restrict__ out) {
    int t = blockIdx.x * blockDim.x + threadIdx.x;
    if (t >= N_NODES * HD) return;
    int c = t & (HD - 1);
    int n = t >> 7;
    const float invN = 1.0f / (float)N_NODES;
    float mu = sums[c] * invN;
    float var = sumsq[c] * invN - mu * mu;
    float v = agg[t] * sinv[n * H1 + (c >> 5)];
    v = (v - mu) * rsqrtf(var + EPS_BN) * gamma[c] + beta[c];
    out[t] = v > 0.f ? v : expm1f(v);
}

// el/er for layer 2: one thread per node, 40-dim dot
__global__ void eler2_k(const float* __restrict__ ft2,
                        const float* __restrict__ al, const float* __restrict__ ar,
                        float* __restrict__ el, float* __restrict__ er) {
    int n = blockIdx.x * blockDim.x + threadIdx.x;
    if (n >= N_NODES) return;
    const float* f = ft2 + (size_t)n * NC;
    float sl = 0.f, sr = 0.f;
    #pragma unroll
    for (int d = 0; d < NC; d += 4) {
        float4 fv = *(const float4*)(f + d);
        float4 av = *(const float4*)(al + d);
        float4 rv = *(const float4*)(ar + d);
        sl += fv.x * av.x + fv.y * av.y + fv.z * av.z + fv.w * av.w;
        sr += fv.x * rv.x + fv.y * rv.y + fv.z * rv.z + fv.w * rv.w;
    }
    el[n] = sl; er[n] = sr;
}

// layer-2 edge aggregation: 16 lanes/edge, lanes 0..9 carry float4 of 40 dims
__global__ void edge_agg2_k(const int* __restrict__ src, const int* __restrict__ dst,
                            const float* __restrict__ ft2,
                            const float* __restrict__ el, const float* __restrict__ er,
                            float* __restrict__ agg, float* __restrict__ s) {
    int gid = blockIdx.x * blockDim.x + threadIdx.x;
    int eid = gid >> 4;
    if (eid >= N_EDGES) return;
    int lane = gid & 15;
    int u = src[eid], v = dst[eid];
    float e = el[u] + er[v];
    e = e > 0.f ? e : SLOPE * e;
    float ex = __expf(e);
    if (lane == 0) atomicAdd(&s[v], ex);
    if (lane < 10) {
        float4 f = *(const float4*)(ft2 + (size_t)u * NC + lane * 4);
        float* out = agg + (size_t)v * NC + lane * 4;
        atomicAdd(out + 0, ex * f.x);
        atomicAdd(out + 1, ex * f.y);
        atomicAdd(out + 2, ex * f.z);
        atomicAdd(out + 3, ex * f.w);
    }
}

// final: logits = agg2/s2, log_softmax per node. one wave (64 lanes) per node
__global__ void final_k(const float* __restrict__ agg2, const float* __restrict__ s2,
                        float* __restrict__ out) {
    int wid = (blockIdx.x * blockDim.x + threadIdx.x) >> 6;
    if (wid >= N_NODES) return;
    int lane = threadIdx.x & 63;
    float sinv = 1.0f / fmaxf(s2[wid], 1e-9f);
    float v = (lane < NC) ? agg2[(size_t)wid * NC + lane] * sinv : -INFINITY;
    float m = v;
    #pragma unroll
    for (int off = 32; off; off >>= 1) m = fmaxf(m, __shfl_xor(m, off));
    float ex = (lane < NC) ? __expf(v - m) : 0.0f;
    float sum = ex;
    #pragma unroll
    for (int off = 32; off; off >>= 1) sum += __shfl_xor(sum, off);
    if (lane < NC) out[(size_t)wid * NC + lane] = v - m - logf(sum);
}

// ---------------------------------------------------------------------------
extern "C" void kernel_launch(void* const* d_in, const int* in_sizes, int n_in,
                              void* d_out, int out_size, void* d_ws, size_t ws_size,
                              hipStream_t stream) {
    const float* x     = (const float*)d_in[0];
    const int*   src   = (const int*)  d_in[1];
    const int*   dst   = (const int*)  d_in[2];
    const float* W1    = (const float*)d_in[3];
    const float* al1   = (const float*)d_in[4];
    const float* ar1   = (const float*)d_in[5];
    const float* gamma = (const float*)d_in[6];
    const float* beta  = (const float*)d_in[7];
    const float* W2    = (const float*)d_in[8];
    const float* al2   = (const float*)d_in[9];
    const float* ar2   = (const float*)d_in[10];
    float* out = (float*)d_out;

    float* ws = (float*)d_ws;
    size_t o = 0;
    // ---- zeroed region (one memset) ----
    float* agg1  = ws + o; o += (size_t)N_NODES * HD;   // 6,400,000
    float* s1    = ws + o; o += (size_t)N_NODES * H1;   //   200,000
    float* agg2  = ws + o; o += (size_t)N_NODES * NC;   // 2,000,000
    float* s2    = ws + o; o += N_NODES;                //    50,000
    float* bnsum = ws + o; o += HD;
    float* bnsq  = ws + o; o += HD;
    size_t zeroBytes = o * sizeof(float);
    // ---- uninitialized region ----
    float* ft1 = ws + o; o += (size_t)N_NODES * HD;     // reused as h after BN
    float* el1 = ws + o; o += (size_t)N_NODES * H1;
    float* er1 = ws + o; o += (size_t)N_NODES * H1;
    float* ft2 = ws + o; o += (size_t)N_NODES * NC;
    float* el2 = ws + o; o += N_NODES;
    float* er2 = ws + o; o += N_NODES;

    hipMemsetAsync(d_ws, 0, zeroBytes, stream);

    // GEMM1: ft1 = x @ W1   (50000x256 @ 256x128)
    {
        dim3 grid((HD + 63) / 64, (N_NODES + 63) / 64);
        sgemm_k<<<grid, 256, 0, stream>>>(x, W1, ft1, N_NODES, HD, IN_DIM);
    }
    eler1_k<<<(N_NODES * H1 + 255) / 256, 256, 0, stream>>>(ft1, al1, ar1, el1, er1);
    {
        long long thr = (long long)N_EDGES * 32;
        edge_agg1_k<<<(int)((thr + 255) / 256), 256, 0, stream>>>(src, dst, ft1, el1, er1, agg1, s1);
    }
    rcp_k<<<(N_NODES * H1 + 255) / 256, 256, 0, stream>>>(s1, N_NODES * H1);
    bnstats_k<<<512, HD, 0, stream>>>(agg1, s1, bnsum, bnsq);
    bnapply_k<<<(N_NODES * HD + 255) / 256, 256, 0, stream>>>(agg1, s1, bnsum, bnsq,
                                                              gamma, beta, ft1);
    // GEMM2: ft2 = h @ W2   (50000x128 @ 128x40)
    {
        dim3 grid((NC + 63) / 64, (N_NODES + 63) / 64);
        sgemm_k<<<grid, 256, 0, stream>>>(ft1, W2, ft2, N_NODES, NC, HD);
    }
    eler2_k<<<(N_NODES + 255) / 256, 256, 0, stream>>>(ft2, al2, ar2, el2, er2);
    {
        long long thr = (long long)N_EDGES * 16;
        edge_agg2_k<<<(int)((thr + 255) / 256), 256, 0, stream>>>(src, dst, ft2, el2, er2, agg2, s2);
    }
    final_k<<<(N_NODES * 64 + 255) / 256, 256, 0, stream>>>(agg2, s2, out);
}

// Round 2
// 517.922 us; speedup vs baseline: 4.3990x; 4.3990x over previous
//
#include <hip/hip_runtime.h>
#include <hip/hip_bf16.h>
#include <math.h>

#define N_NODES 50000
#define N_EDGES 850000
#define IN_DIM  256
#define HD      128      // H1*D
#define H1      4
#define D       32
#define NC      40       // num classes
#define SLOPE   0.2f
#define EPS_BN  1e-5f

// ---------------------------------------------------------------------------
// fp32 tiled SGEMM: C = A(MxK) @ B(KxN). 64x64 tile, BK=16, 256 thr, 4x4/thread
// ---------------------------------------------------------------------------
__global__ __launch_bounds__(256) void sgemm_k(const float* __restrict__ A,
                                               const float* __restrict__ B,
                                               float* __restrict__ Cm,
                                               int M, int N, int K) {
    __shared__ float As[16][68];   // transposed, +4 pad
    __shared__ float Bs[16][64];
    int tid = threadIdx.x;
    int tx = tid & 15, ty = tid >> 4;
    int rowBase = blockIdx.y * 64, colBase = blockIdx.x * 64;
    int arow = tid >> 2, akk = (tid & 3) << 2;     // A: 64 rows x 16 k, float4 on k
    int brow = tid >> 4, bcol = (tid & 15) << 2;   // B: 16 k x 64 cols, float4 on col
    float acc[4][4] = {};
    for (int k0 = 0; k0 < K; k0 += 16) {
        float4 av = make_float4(0.f, 0.f, 0.f, 0.f);
        int gr = rowBase + arow;
        if (gr < M) av = *(const float4*)(A + (size_t)gr * K + k0 + akk);
        As[akk + 0][arow] = av.x; As[akk + 1][arow] = av.y;
        As[akk + 2][arow] = av.z; As[akk + 3][arow] = av.w;
        float4 bv = make_float4(0.f, 0.f, 0.f, 0.f);
        int gc = colBase + bcol;
        if (gc + 3 < N) bv = *(const float4*)(B + (size_t)(k0 + brow) * N + gc);
        *(float4*)(&Bs[brow][bcol]) = bv;
        __syncthreads();
        #pragma unroll
        for (int k = 0; k < 16; ++k) {
            float a[4], b[4];
            #pragma unroll
            for (int i = 0; i < 4; ++i) a[i] = As[k][ty * 4 + i];
            #pragma unroll
            for (int j = 0; j < 4; ++j) b[j] = Bs[k][tx * 4 + j];
            #pragma unroll
            for (int i = 0; i < 4; ++i)
                #pragma unroll
                for (int j = 0; j < 4; ++j)
                    acc[i][j] = fmaf(a[i], b[j], acc[i][j]);
        }
        __syncthreads();
    }
    #pragma unroll
    for (int i = 0; i < 4; ++i) {
        int r = rowBase + ty * 4 + i;
        if (r >= M) continue;
        #pragma unroll
        for (int j = 0; j < 4; ++j) {
            int c = colBase + tx * 4 + j;
            if (c < N) Cm[(size_t)r * N + c] = acc[i][j];
        }
    }
}

// ---------------------------------------------------------------------------
// CSR build: histogram -> 2-level exclusive scan -> scatter with per-node cursor
// ---------------------------------------------------------------------------
__global__ void hist_k(const int* __restrict__ dst, int* __restrict__ cnt) {
    int e = blockIdx.x * blockDim.x + threadIdx.x;
    if (e < N_EDGES) atomicAdd(&cnt[dst[e]], 1);
}

// block-level exclusive scan of 256 elements; emits block totals
__global__ void scan1_k(const int* __restrict__ cnt, int* __restrict__ rowpart,
                        int* __restrict__ bsum) {
    __shared__ int sh[256];
    int i = blockIdx.x * 256 + threadIdx.x;
    int v = (i < N_NODES) ? cnt[i] : 0;
    sh[threadIdx.x] = v;
    __syncthreads();
    #pragma unroll
    for (int off = 1; off < 256; off <<= 1) {
        int t = (threadIdx.x >= off) ? sh[threadIdx.x - off] : 0;
        __syncthreads();
        sh[threadIdx.x] += t;
        __syncthreads();
    }
    if (i < N_NODES) rowpart[i] = sh[threadIdx.x] - v;   // exclusive
    if (threadIdx.x == 255) bsum[blockIdx.x] = sh[255];
}

// exclusive scan of the (<=256) block sums, in place
__global__ void scan2_k(int* __restrict__ bsum, int nb) {
    __shared__ int sh[256];
    int v = (threadIdx.x < nb) ? bsum[threadIdx.x] : 0;
    sh[threadIdx.x] = v;
    __syncthreads();
    #pragma unroll
    for (int off = 1; off < 256; off <<= 1) {
        int t = (threadIdx.x >= off) ? sh[threadIdx.x - off] : 0;
        __syncthreads();
        sh[threadIdx.x] += t;
        __syncthreads();
    }
    bsum[threadIdx.x] = sh[threadIdx.x] - v;
}

__global__ void scan3_k(const int* __restrict__ rowpart, const int* __restrict__ bsum,
                        int* __restrict__ row) {
    int i = blockIdx.x * blockDim.x + threadIdx.x;
    if (i < N_NODES) row[i] = rowpart[i] + bsum[i >> 8];
    if (i == N_NODES) row[N_NODES] = N_EDGES;
}

__global__ void scatter_k(const int* __restrict__ src, const int* __restrict__ dst,
                          const int* __restrict__ row, int* __restrict__ cursor,
                          int* __restrict__ csr_src) {
    int e = blockIdx.x * blockDim.x + threadIdx.x;
    if (e >= N_EDGES) return;
    int v = dst[e];
    int slot = row[v] + atomicAdd(&cursor[v], 1);
    csr_src[slot] = src[e];
}

// ---------------------------------------------------------------------------
// el/er for layer 1: one thread per (node, head); reads 32 floats of ft row
// ---------------------------------------------------------------------------
__global__ void eler1_k(const float* __restrict__ ft,
                        const float* __restrict__ al, const float* __restrict__ ar,
                        float* __restrict__ el, float* __restrict__ er) {
    int t = blockIdx.x * blockDim.x + threadIdx.x;
    if (t >= N_NODES * H1) return;
    int n = t >> 2, h = t & 3;
    const float* f = ft + (size_t)n * HD + h * D;
    const float* a = al + h * D;
    const float* r = ar + h * D;
    float sl = 0.f, sr = 0.f;
    #pragma unroll
    for (int d = 0; d < D; d += 4) {
        float4 fv = *(const float4*)(f + d);
        float4 av = *(const float4*)(a + d);
        float4 rv = *(const float4*)(r + d);
        sl += fv.x * av.x + fv.y * av.y + fv.z * av.z + fv.w * av.w;
        sr += fv.x * rv.x + fv.y * rv.y + fv.z * rv.z + fv.w * rv.w;
    }
    el[t] = sl; er[t] = sr;
}

// ---------------------------------------------------------------------------
// layer-1 gather: one wave per dst node; lane owns float2 of the 128 dims.
// head = lane>>4; per-lane ssum equals the head's softmax denom (all lanes of
// a head compute identical ex). Writes normalized h1 = agg/s. No atomics.
// (segment-max skipped: |e| small here, softmax shift-invariant in fp32)
// ---------------------------------------------------------------------------
__global__ __launch_bounds__(256) void gather1_k(const int* __restrict__ row,
                                                 const int* __restrict__ csr_src,
                                                 const float* __restrict__ ft,
                                                 const float* __restrict__ el,
                                                 const float* __restrict__ er,
                                                 float* __restrict__ h1) {
    int w = (blockIdx.x * blockDim.x + threadIdx.x) >> 6;   // node
    if (w >= N_NODES) return;
    int lane = threadIdx.x & 63;
    int hh = lane >> 4;
    float erv = er[w * H1 + hh];
    int jb = row[w], je = row[w + 1];
    float ax = 0.f, ay = 0.f, ssum = 0.f;
    for (int j = jb; j < je; ++j) {
        int u = csr_src[j];
        float e1 = el[u * H1 + hh] + erv;
        e1 = e1 > 0.f ? e1 : SLOPE * e1;
        float ex = __expf(e1);
        float2 f = *(const float2*)(ft + (size_t)u * HD + lane * 2);
        ax = fmaf(ex, f.x, ax);
        ay = fmaf(ex, f.y, ay);
        ssum += ex;
    }
    float inv = 1.0f / fmaxf(ssum, 1e-9f);
    *(float2*)(h1 + (size_t)w * HD + lane * 2) = make_float2(ax * inv, ay * inv);
}

// ---------------------------------------------------------------------------
// BN stats: per-feature sum & sumsq of h1 (128 features)
// ---------------------------------------------------------------------------
__global__ void bnstats_k(const float* __restrict__ h1,
                          float* __restrict__ sums, float* __restrict__ sumsq) {
    int c = threadIdx.x;  // 128 threads
    float acc = 0.f, acc2 = 0.f;
    for (int r = blockIdx.x; r < N_NODES; r += gridDim.x) {
        float v = h1[(size_t)r * HD + c];
        acc += v; acc2 += v * v;
    }
    atomicAdd(&sums[c], acc);
    atomicAdd(&sumsq[c], acc2);
}

// BN apply + ELU, in place on h1
__global__ void bnapply_k(float* __restrict__ h1,
                          const float* __restrict__ sums, const float* __restrict__ sumsq,
                          const float* __restrict__ gamma, const float* __restrict__ beta) {
    int t = blockIdx.x * blockDim.x + threadIdx.x;
    if (t >= N_NODES * HD) return;
    int c = t & (HD - 1);
    const float invN = 1.0f / (float)N_NODES;
    float mu = sums[c] * invN;
    float var = sumsq[c] * invN - mu * mu;
    float v = h1[t];
    v = (v - mu) * rsqrtf(var + EPS_BN) * gamma[c] + beta[c];
    h1[t] = v > 0.f ? v : expm1f(v);
}

// el/er for layer 2: one thread per node, 40-dim dot
__global__ void eler2_k(const float* __restrict__ ft2,
                        const float* __restrict__ al, const float* __restrict__ ar,
                        float* __restrict__ el, float* __restrict__ er) {
    int n = blockIdx.x * blockDim.x + threadIdx.x;
    if (n >= N_NODES) return;
    const float* f = ft2 + (size_t)n * NC;
    float sl = 0.f, sr = 0.f;
    #pragma unroll
    for (int d = 0; d < NC; d += 4) {
        float4 fv = *(const float4*)(f + d);
        float4 av = *(const float4*)(al + d);
        float4 rv = *(const float4*)(ar + d);
        sl += fv.x * av.x + fv.y * av.y + fv.z * av.z + fv.w * av.w;
        sr += fv.x * rv.x + fv.y * rv.y + fv.z * rv.z + fv.w * rv.w;
    }
    el[n] = sl; er[n] = sr;
}

// ---------------------------------------------------------------------------
// layer-2 gather fused with log_softmax: one wave per dst node; lanes 0..39
// own one class dim. All lanes compute identical ex -> per-lane ssum = denom.
// ---------------------------------------------------------------------------
__global__ __launch_bounds__(256) void gather2_k(const int* __restrict__ row,
                                                 const int* __restrict__ csr_src,
                                                 const float* __restrict__ ft2,
                                                 const float* __restrict__ el,
                                                 const float* __restrict__ er,
                                                 float* __restrict__ out) {
    int w = (blockIdx.x * blockDim.x + threadIdx.x) >> 6;   // node
    if (w >= N_NODES) return;
    int lane = threadIdx.x & 63;
    float erv = er[w];
    int jb = row[w], je = row[w + 1];
    float acc = 0.f, ssum = 0.f;
    for (int j = jb; j < je; ++j) {
        int u = csr_src[j];
        float e1 = el[u] + erv;
        e1 = e1 > 0.f ? e1 : SLOPE * e1;
        float ex = __expf(e1);
        float f = (lane < NC) ? ft2[(size_t)u * NC + lane] : 0.f;
        acc = fmaf(ex, f, acc);
        ssum += ex;
    }
    float v = acc / fmaxf(ssum, 1e-9f);
    float vv = (lane < NC) ? v : -INFINITY;
    float m = vv;
    #pragma unroll
    for (int off = 32; off; off >>= 1) m = fmaxf(m, __shfl_xor(m, off));
    float ex2 = (lane < NC) ? __expf(vv - m) : 0.f;
    float sum = ex2;
    #pragma unroll
    for (int off = 32; off; off >>= 1) sum += __shfl_xor(sum, off);
    if (lane < NC) out[(size_t)w * NC + lane] = vv - m - logf(sum);
}

// ---------------------------------------------------------------------------
extern "C" void kernel_launch(void* const* d_in, const int* in_sizes, int n_in,
                              void* d_out, int out_size, void* d_ws, size_t ws_size,
                              hipStream_t stream) {
    const float* x     = (const float*)d_in[0];
    const int*   src   = (const int*)  d_in[1];
    const int*   dst   = (const int*)  d_in[2];
    const float* W1    = (const float*)d_in[3];
    const float* al1   = (const float*)d_in[4];
    const float* ar1   = (const float*)d_in[5];
    const float* gamma = (const float*)d_in[6];
    const float* beta  = (const float*)d_in[7];
    const float* W2    = (const float*)d_in[8];
    const float* al2   = (const float*)d_in[9];
    const float* ar2   = (const float*)d_in[10];
    float* out = (float*)d_out;

    char* ws = (char*)d_ws;
    size_t o = 0;
    auto alloc = [&](size_t elems) { void* p = ws + o; o += elems * 4; return p; };
    // ---- zeroed region (one small memset) ----
    int*   cnt    = (int*)alloc(N_NODES);
    int*   cursor = (int*)alloc(N_NODES);
    float* bnsum  = (float*)alloc(HD);
    float* bnsq   = (float*)alloc(HD);
    size_t zeroBytes = o;
    // ---- uninitialized region ----
    int*   rowpart = (int*)alloc(N_NODES);
    int*   bsum    = (int*)alloc(256);
    int*   rowp    = (int*)alloc(N_NODES + 1);
    int*   csr_src = (int*)alloc(N_EDGES);
    float* ft1 = (float*)alloc((size_t)N_NODES * HD);
    float* h1  = (float*)alloc((size_t)N_NODES * HD);
    float* el1 = (float*)alloc(N_NODES * H1);
    float* er1 = (float*)alloc(N_NODES * H1);
    float* ft2 = (float*)alloc((size_t)N_NODES * NC);
    float* el2 = (float*)alloc(N_NODES);
    float* er2 = (float*)alloc(N_NODES);

    hipMemsetAsync(d_ws, 0, zeroBytes, stream);

    const int NB_SCAN = (N_NODES + 255) / 256;            // 196
    const int NB_E    = (N_EDGES + 255) / 256;            // 3321

    // CSR build (by destination)
    hist_k   <<<NB_E, 256, 0, stream>>>(dst, cnt);
    scan1_k  <<<NB_SCAN, 256, 0, stream>>>(cnt, rowpart, bsum);
    scan2_k  <<<1, 256, 0, stream>>>(bsum, NB_SCAN);
    scan3_k  <<<(N_NODES + 256) / 256 + 1, 256, 0, stream>>>(rowpart, bsum, rowp);
    scatter_k<<<NB_E, 256, 0, stream>>>(src, dst, rowp, cursor, csr_src);

    // GEMM1: ft1 = x @ W1   (50000x256 @ 256x128)
    {
        dim3 grid((HD + 63) / 64, (N_NODES + 63) / 64);
        sgemm_k<<<grid, 256, 0, stream>>>(x, W1, ft1, N_NODES, HD, IN_DIM);
    }
    eler1_k<<<(N_NODES * H1 + 255) / 256, 256, 0, stream>>>(ft1, al1, ar1, el1, er1);
    gather1_k<<<N_NODES / 4, 256, 0, stream>>>(rowp, csr_src, ft1, el1, er1, h1);

    bnstats_k<<<512, HD, 0, stream>>>(h1, bnsum, bnsq);
    bnapply_k<<<(N_NODES * HD + 255) / 256, 256, 0, stream>>>(h1, bnsum, bnsq, gamma, beta);

    // GEMM2: ft2 = h1 @ W2   (50000x128 @ 128x40)
    {
        dim3 grid((NC + 63) / 64, (N_NODES + 63) / 64);
        sgemm_k<<<grid, 256, 0, stream>>>(h1, W2, ft2, N_NODES, NC, HD);
    }
    eler2_k<<<(N_NODES + 255) / 256, 256, 0, stream>>>(ft2, al2, ar2, el2, er2);
    gather2_k<<<N_NODES / 4, 256, 0, stream>>>(rowp, csr_src, ft2, el2, er2, out);
}

// Round 3
// 454.174 us; speedup vs baseline: 5.0164x; 1.1404x over previous
//
#include <hip/hip_runtime.h>
#include <hip/hip_bf16.h>
#include <math.h>

#define N_NODES 50000
#define N_EDGES 850000
#define IN_DIM  256
#define HD      128      // H1*D
#define H1      4
#define D       32
#define NC      40       // num classes
#define SLOPE   0.2f
#define EPS_BN  1e-5f

__device__ __forceinline__ unsigned short f2bf(float x) {
    union { float f; unsigned u; } v; v.f = x;
    unsigned r = v.u + 0x7FFF + ((v.u >> 16) & 1);   // RNE
    return (unsigned short)(r >> 16);
}
__device__ __forceinline__ float bf2f(unsigned short h) {
    union { unsigned u; float f; } v; v.u = ((unsigned)h) << 16;
    return v.f;
}

// ---------------------------------------------------------------------------
// fp32 tiled SGEMM, 64x64 tile, BK=16, 256 thr, 4x4/thread.
// Optional BN+ELU transform on A elements (per-K-column scale/shift).
// Writes fp32 C and bf16 copy Cb.
// ---------------------------------------------------------------------------
template<bool BN_A>
__global__ __launch_bounds__(256) void sgemm_k(const float* __restrict__ A,
                                               const float* __restrict__ B,
                                               float* __restrict__ Cf,
                                               unsigned short* __restrict__ Cb,
                                               const float* __restrict__ scale,
                                               const float* __restrict__ shift,
                                               int M, int N, int K) {
    __shared__ float As[16][68];   // transposed, +4 pad
    __shared__ float Bs[16][64];
    int tid = threadIdx.x;
    int tx = tid & 15, ty = tid >> 4;
    int rowBase = blockIdx.y * 64, colBase = blockIdx.x * 64;
    int arow = tid >> 2, akk = (tid & 3) << 2;     // A: 64 rows x 16 k, float4 on k
    int brow = tid >> 4, bcol = (tid & 15) << 2;   // B: 16 k x 64 cols, float4 on col
    float acc[4][4] = {};
    for (int k0 = 0; k0 < K; k0 += 16) {
        float4 av = make_float4(0.f, 0.f, 0.f, 0.f);
        int gr = rowBase + arow;
        if (gr < M) {
            av = *(const float4*)(A + (size_t)gr * K + k0 + akk);
            if (BN_A) {
                int c = k0 + akk;
                av.x = fmaf(av.x, scale[c + 0], shift[c + 0]);
                av.y = fmaf(av.y, scale[c + 1], shift[c + 1]);
                av.z = fmaf(av.z, scale[c + 2], shift[c + 2]);
                av.w = fmaf(av.w, scale[c + 3], shift[c + 3]);
                av.x = av.x > 0.f ? av.x : expm1f(av.x);
                av.y = av.y > 0.f ? av.y : expm1f(av.y);
                av.z = av.z > 0.f ? av.z : expm1f(av.z);
                av.w = av.w > 0.f ? av.w : expm1f(av.w);
            }
        }
        As[akk + 0][arow] = av.x; As[akk + 1][arow] = av.y;
        As[akk + 2][arow] = av.z; As[akk + 3][arow] = av.w;
        float4 bv = make_float4(0.f, 0.f, 0.f, 0.f);
        int gc = colBase + bcol;
        if (gc + 3 < N) bv = *(const float4*)(B + (size_t)(k0 + brow) * N + gc);
        *(float4*)(&Bs[brow][bcol]) = bv;
        __syncthreads();
        #pragma unroll
        for (int k = 0; k < 16; ++k) {
            float a[4], b[4];
            #pragma unroll
            for (int i = 0; i < 4; ++i) a[i] = As[k][ty * 4 + i];
            #pragma unroll
            for (int j = 0; j < 4; ++j) b[j] = Bs[k][tx * 4 + j];
            #pragma unroll
            for (int i = 0; i < 4; ++i)
                #pragma unroll
                for (int j = 0; j < 4; ++j)
                    acc[i][j] = fmaf(a[i], b[j], acc[i][j]);
        }
        __syncthreads();
    }
    #pragma unroll
    for (int i = 0; i < 4; ++i) {
        int r = rowBase + ty * 4 + i;
        if (r >= M) continue;
        #pragma unroll
        for (int j = 0; j < 4; ++j) {
            int c = colBase + tx * 4 + j;
            if (c < N) {
                Cf[(size_t)r * N + c] = acc[i][j];
                Cb[(size_t)r * N + c] = f2bf(acc[i][j]);
            }
        }
    }
}

// ---------------------------------------------------------------------------
// CSR build: histogram -> 2-level exclusive scan -> scatter with per-node cursor
// ---------------------------------------------------------------------------
__global__ void hist_k(const int* __restrict__ dst, int* __restrict__ cnt) {
    int e = blockIdx.x * blockDim.x + threadIdx.x;
    if (e < N_EDGES) atomicAdd(&cnt[dst[e]], 1);
}

__global__ void scan1_k(const int* __restrict__ cnt, int* __restrict__ rowpart,
                        int* __restrict__ bsum) {
    __shared__ int sh[256];
    int i = blockIdx.x * 256 + threadIdx.x;
    int v = (i < N_NODES) ? cnt[i] : 0;
    sh[threadIdx.x] = v;
    __syncthreads();
    #pragma unroll
    for (int off = 1; off < 256; off <<= 1) {
        int t = (threadIdx.x >= off) ? sh[threadIdx.x - off] : 0;
        __syncthreads();
        sh[threadIdx.x] += t;
        __syncthreads();
    }
    if (i < N_NODES) rowpart[i] = sh[threadIdx.x] - v;   // exclusive
    if (threadIdx.x == 255) bsum[blockIdx.x] = sh[255];
}

__global__ void scan2_k(int* __restrict__ bsum, int nb) {
    __shared__ int sh[256];
    int v = (threadIdx.x < nb) ? bsum[threadIdx.x] : 0;
    sh[threadIdx.x] = v;
    __syncthreads();
    #pragma unroll
    for (int off = 1; off < 256; off <<= 1) {
        int t = (threadIdx.x >= off) ? sh[threadIdx.x - off] : 0;
        __syncthreads();
        sh[threadIdx.x] += t;
        __syncthreads();
    }
    bsum[threadIdx.x] = sh[threadIdx.x] - v;
}

__global__ void scan3_k(const int* __restrict__ rowpart, const int* __restrict__ bsum,
                        int* __restrict__ row) {
    int i = blockIdx.x * blockDim.x + threadIdx.x;
    if (i < N_NODES) row[i] = rowpart[i] + bsum[i >> 8];
    if (i == N_NODES) row[N_NODES] = N_EDGES;
}

__global__ void scatter_k(const int* __restrict__ src, const int* __restrict__ dst,
                          const int* __restrict__ row, int* __restrict__ cursor,
                          int* __restrict__ csr_src) {
    int e = blockIdx.x * blockDim.x + threadIdx.x;
    if (e >= N_EDGES) return;
    int v = dst[e];
    int slot = row[v] + atomicAdd(&cursor[v], 1);
    csr_src[slot] = src[e];
}

// ---------------------------------------------------------------------------
// el/er for layer 1: one thread per (node, head)
// ---------------------------------------------------------------------------
__global__ void eler1_k(const float* __restrict__ ft,
                        const float* __restrict__ al, const float* __restrict__ ar,
                        float* __restrict__ el, float* __restrict__ er) {
    int t = blockIdx.x * blockDim.x + threadIdx.x;
    if (t >= N_NODES * H1) return;
    int n = t >> 2, h = t & 3;
    const float* f = ft + (size_t)n * HD + h * D;
    const float* a = al + h * D;
    const float* r = ar + h * D;
    float sl = 0.f, sr = 0.f;
    #pragma unroll
    for (int d = 0; d < D; d += 4) {
        float4 fv = *(const float4*)(f + d);
        float4 av = *(const float4*)(a + d);
        float4 rv = *(const float4*)(r + d);
        sl += fv.x * av.x + fv.y * av.y + fv.z * av.z + fv.w * av.w;
        sr += fv.x * rv.x + fv.y * rv.y + fv.z * rv.z + fv.w * rv.w;
    }
    el[t] = sl; er[t] = sr;
}

// ---------------------------------------------------------------------------
// layer-1 gather: one wave per dst node; lane owns bf16x2 of the 128 dims.
// attention weights fp32; features bf16. Writes raw (pre-BN) h1 = agg/s.
// ---------------------------------------------------------------------------
__global__ __launch_bounds__(256) void gather1_k(const int* __restrict__ row,
                                                 const int* __restrict__ csr_src,
                                                 const unsigned short* __restrict__ ftb,
                                                 const float* __restrict__ el,
                                                 const float* __restrict__ er,
                                                 float* __restrict__ h1) {
    int w = (blockIdx.x * blockDim.x + threadIdx.x) >> 6;   // node
    if (w >= N_NODES) return;
    int lane = threadIdx.x & 63;
    int hh = lane >> 4;
    float erv = er[w * H1 + hh];
    int jb = row[w], je = row[w + 1];
    float ax = 0.f, ay = 0.f, ssum = 0.f;
    int j = jb;
    for (; j + 1 < je; j += 2) {
        int u0 = csr_src[j], u1 = csr_src[j + 1];
        float e0 = el[u0 * H1 + hh] + erv;
        float e1 = el[u1 * H1 + hh] + erv;
        e0 = e0 > 0.f ? e0 : SLOPE * e0;
        e1 = e1 > 0.f ? e1 : SLOPE * e1;
        float x0 = __expf(e0), x1 = __expf(e1);
        ushort2 f0 = *(const ushort2*)(ftb + (size_t)u0 * HD + lane * 2);
        ushort2 f1 = *(const ushort2*)(ftb + (size_t)u1 * HD + lane * 2);
        ax = fmaf(x0, bf2f(f0.x), ax); ay = fmaf(x0, bf2f(f0.y), ay);
        ax = fmaf(x1, bf2f(f1.x), ax); ay = fmaf(x1, bf2f(f1.y), ay);
        ssum += x0 + x1;
    }
    if (j < je) {
        int u0 = csr_src[j];
        float e0 = el[u0 * H1 + hh] + erv;
        e0 = e0 > 0.f ? e0 : SLOPE * e0;
        float x0 = __expf(e0);
        ushort2 f0 = *(const ushort2*)(ftb + (size_t)u0 * HD + lane * 2);
        ax = fmaf(x0, bf2f(f0.x), ax); ay = fmaf(x0, bf2f(f0.y), ay);
        ssum += x0;
    }
    float inv = 1.0f / fmaxf(ssum, 1e-9f);
    *(float2*)(h1 + (size_t)w * HD + lane * 2) = make_float2(ax * inv, ay * inv);
}

// ---------------------------------------------------------------------------
// BN stats on raw h1; then tiny kernel folds to per-column scale/shift
// ---------------------------------------------------------------------------
__global__ void bnstats_k(const float* __restrict__ h1,
                          float* __restrict__ sums, float* __restrict__ sumsq) {
    int c = threadIdx.x;  // 128 threads
    float acc = 0.f, acc2 = 0.f;
    for (int r = blockIdx.x; r < N_NODES; r += gridDim.x) {
        float v = h1[(size_t)r * HD + c];
        acc += v; acc2 += v * v;
    }
    atomicAdd(&sums[c], acc);
    atomicAdd(&sumsq[c], acc2);
}

__global__ void bnscale_k(const float* __restrict__ sums, const float* __restrict__ sumsq,
                          const float* __restrict__ gamma, const float* __restrict__ beta,
                          float* __restrict__ scale, float* __restrict__ shift) {
    int c = threadIdx.x;  // 128
    const float invN = 1.0f / (float)N_NODES;
    float mu = sums[c] * invN;
    float var = sumsq[c] * invN - mu * mu;
    float sc = gamma[c] * rsqrtf(var + EPS_BN);
    scale[c] = sc;
    shift[c] = beta[c] - mu * sc;
}

// el/er for layer 2: one thread per node, 40-dim dot
__global__ void eler2_k(const float* __restrict__ ft2,
                        const float* __restrict__ al, const float* __restrict__ ar,
                        float* __restrict__ el, float* __restrict__ er) {
    int n = blockIdx.x * blockDim.x + threadIdx.x;
    if (n >= N_NODES) return;
    const float* f = ft2 + (size_t)n * NC;
    float sl = 0.f, sr = 0.f;
    #pragma unroll
    for (int d = 0; d < NC; d += 4) {
        float4 fv = *(const float4*)(f + d);
        float4 av = *(const float4*)(al + d);
        float4 rv = *(const float4*)(ar + d);
        sl += fv.x * av.x + fv.y * av.y + fv.z * av.z + fv.w * av.w;
        sr += fv.x * rv.x + fv.y * rv.y + fv.z * rv.z + fv.w * rv.w;
    }
    el[n] = sl; er[n] = sr;
}

// ---------------------------------------------------------------------------
// layer-2 gather fused with log_softmax: one wave per dst node; lanes 0..39
// own one class dim (bf16 features).
// ---------------------------------------------------------------------------
__global__ __launch_bounds__(256) void gather2_k(const int* __restrict__ row,
                                                 const int* __restrict__ csr_src,
                                                 const unsigned short* __restrict__ ft2b,
                                                 const float* __restrict__ el,
                                                 const float* __restrict__ er,
                                                 float* __restrict__ out) {
    int w = (blockIdx.x * blockDim.x + threadIdx.x) >> 6;   // node
    if (w >= N_NODES) return;
    int lane = threadIdx.x & 63;
    float erv = er[w];
    int jb = row[w], je = row[w + 1];
    float acc = 0.f, ssum = 0.f;
    int j = jb;
    for (; j + 1 < je; j += 2) {
        int u0 = csr_src[j], u1 = csr_src[j + 1];
        float e0 = el[u0] + erv, e1 = el[u1] + erv;
        e0 = e0 > 0.f ? e0 : SLOPE * e0;
        e1 = e1 > 0.f ? e1 : SLOPE * e1;
        float x0 = __expf(e0), x1 = __expf(e1);
        float fa = (lane < NC) ? bf2f(ft2b[(size_t)u0 * NC + lane]) : 0.f;
        float fb = (lane < NC) ? bf2f(ft2b[(size_t)u1 * NC + lane]) : 0.f;
        acc = fmaf(x0, fa, acc);
        acc = fmaf(x1, fb, acc);
        ssum += x0 + x1;
    }
    if (j < je) {
        int u0 = csr_src[j];
        float e0 = el[u0] + erv;
        e0 = e0 > 0.f ? e0 : SLOPE * e0;
        float x0 = __expf(e0);
        float fa = (lane < NC) ? bf2f(ft2b[(size_t)u0 * NC + lane]) : 0.f;
        acc = fmaf(x0, fa, acc);
        ssum += x0;
    }
    float v = acc / fmaxf(ssum, 1e-9f);
    float vv = (lane < NC) ? v : -INFINITY;
    float m = vv;
    #pragma unroll
    for (int off = 32; off; off >>= 1) m = fmaxf(m, __shfl_xor(m, off));
    float ex2 = (lane < NC) ? __expf(vv - m) : 0.f;
    float sum = ex2;
    #pragma unroll
    for (int off = 32; off; off >>= 1) sum += __shfl_xor(sum, off);
    if (lane < NC) out[(size_t)w * NC + lane] = vv - m - logf(sum);
}

// ---------------------------------------------------------------------------
extern "C" void kernel_launch(void* const* d_in, const int* in_sizes, int n_in,
                              void* d_out, int out_size, void* d_ws, size_t ws_size,
                              hipStream_t stream) {
    const float* x     = (const float*)d_in[0];
    const int*   src   = (const int*)  d_in[1];
    const int*   dst   = (const int*)  d_in[2];
    const float* W1    = (const float*)d_in[3];
    const float* al1   = (const float*)d_in[4];
    const float* ar1   = (const float*)d_in[5];
    const float* gamma = (const float*)d_in[6];
    const float* beta  = (const float*)d_in[7];
    const float* W2    = (const float*)d_in[8];
    const float* al2   = (const float*)d_in[9];
    const float* ar2   = (const float*)d_in[10];
    float* out = (float*)d_out;

    char* ws = (char*)d_ws;
    size_t o = 0;
    auto allocB = [&](size_t bytes) { void* p = ws + o; o += (bytes + 15) & ~15ull; return p; };
    // ---- zeroed region (one small memset) ----
    int*   cnt    = (int*)allocB(N_NODES * 4);
    int*   cursor = (int*)allocB(N_NODES * 4);
    float* bnsum  = (float*)allocB(HD * 4);
    float* bnsq   = (float*)allocB(HD * 4);
    size_t zeroBytes = o;
    // ---- uninitialized region ----
    int*   rowpart = (int*)allocB(N_NODES * 4);
    int*   bsum    = (int*)allocB(256 * 4);
    int*   rowp    = (int*)allocB((N_NODES + 1) * 4);
    int*   csr_src = (int*)allocB(N_EDGES * 4);
    float* ft1  = (float*)allocB((size_t)N_NODES * HD * 4);
    unsigned short* ft1b = (unsigned short*)allocB((size_t)N_NODES * HD * 2);
    float* h1   = (float*)allocB((size_t)N_NODES * HD * 4);
    float* el1  = (float*)allocB(N_NODES * H1 * 4);
    float* er1  = (float*)allocB(N_NODES * H1 * 4);
    float* ft2  = (float*)allocB((size_t)N_NODES * NC * 4);
    unsigned short* ft2b = (unsigned short*)allocB((size_t)N_NODES * NC * 2);
    float* el2  = (float*)allocB(N_NODES * 4);
    float* er2  = (float*)allocB(N_NODES * 4);
    float* bnscale = (float*)allocB(HD * 4);
    float* bnshift = (float*)allocB(HD * 4);

    hipMemsetAsync(d_ws, 0, zeroBytes, stream);

    const int NB_SCAN = (N_NODES + 255) / 256;            // 196
    const int NB_E    = (N_EDGES + 255) / 256;            // 3321

    // CSR build (by destination)
    hist_k   <<<NB_E, 256, 0, stream>>>(dst, cnt);
    scan1_k  <<<NB_SCAN, 256, 0, stream>>>(cnt, rowpart, bsum);
    scan2_k  <<<1, 256, 0, stream>>>(bsum, NB_SCAN);
    scan3_k  <<<(N_NODES + 256) / 256 + 1, 256, 0, stream>>>(rowpart, bsum, rowp);
    scatter_k<<<NB_E, 256, 0, stream>>>(src, dst, rowp, cursor, csr_src);

    // GEMM1: ft1 = x @ W1   (50000x256 @ 256x128), dual fp32+bf16 output
    {
        dim3 grid((HD + 63) / 64, (N_NODES + 63) / 64);
        sgemm_k<false><<<grid, 256, 0, stream>>>(x, W1, ft1, ft1b, nullptr, nullptr,
                                                 N_NODES, HD, IN_DIM);
    }
    eler1_k<<<(N_NODES * H1 + 255) / 256, 256, 0, stream>>>(ft1, al1, ar1, el1, er1);
    gather1_k<<<N_NODES / 4, 256, 0, stream>>>(rowp, csr_src, ft1b, el1, er1, h1);

    bnstats_k<<<512, HD, 0, stream>>>(h1, bnsum, bnsq);
    bnscale_k<<<1, HD, 0, stream>>>(bnsum, bnsq, gamma, beta, bnscale, bnshift);

    // GEMM2: ft2 = elu(bn(h1)) @ W2  (50000x128 @ 128x40), BN+ELU fused on A-load
    {
        dim3 grid((NC + 63) / 64, (N_NODES + 63) / 64);
        sgemm_k<true><<<grid, 256, 0, stream>>>(h1, W2, ft2, ft2b, bnscale, bnshift,
                                                N_NODES, NC, HD);
    }
    eler2_k<<<(N_NODES + 255) / 256, 256, 0, stream>>>(ft2, al2, ar2, el2, er2);
    gather2_k<<<N_NODES / 4, 256, 0, stream>>>(rowp, csr_src, ft2b, el2, er2, out);
}

// Round 4
// 396.785 us; speedup vs baseline: 5.7420x; 1.1446x over previous
//
#include <hip/hip_runtime.h>
#include <hip/hip_bf16.h>
#include <math.h>

#define N_NODES 50000
#define N_EDGES 850000
#define IN_DIM  256
#define HD      128      // H1*D
#define H1      4
#define D       32
#define NC      40       // num classes
#define SLOPE   0.2f
#define EPS_BN  1e-5f

typedef __attribute__((ext_vector_type(8))) short bf16x8;
typedef __attribute__((ext_vector_type(4))) float f32x4;

__device__ __forceinline__ unsigned short f2bf(float x) {
    union { float f; unsigned u; } v; v.f = x;
    unsigned r = v.u + 0x7FFF + ((v.u >> 16) & 1);   // RNE
    return (unsigned short)(r >> 16);
}
__device__ __forceinline__ float bf2f(unsigned short h) {
    union { unsigned u; float f; } v; v.u = ((unsigned)h) << 16;
    return v.f;
}
__device__ __forceinline__ uint4 pack8(float a0,float a1,float a2,float a3,
                                       float a4,float a5,float a6,float a7) {
    uint4 p;
    p.x = f2bf(a0) | ((unsigned)f2bf(a1) << 16);
    p.y = f2bf(a2) | ((unsigned)f2bf(a3) << 16);
    p.z = f2bf(a4) | ((unsigned)f2bf(a5) << 16);
    p.w = f2bf(a6) | ((unsigned)f2bf(a7) << 16);
    return p;
}

// chunk-swizzled [rows][32] bf16 tile: 4 chunks of 8 bf16 per row (64B rows).
// pos = chunk ^ ((row>>1)&3) -> 2-way max on frag reads. Returns short index.
__device__ __forceinline__ int tile32_addr(int row, int chunk) {
    return row * 32 + ((chunk ^ ((row >> 1) & 3)) << 3);
}

// ---------------------------------------------------------------------------
// Weight prep: W1t bf16 [128][256] = W1^T; W2t bf16 [48][128] = W2^T (pad 0)
// ---------------------------------------------------------------------------
__global__ void cvtw_k(const float* __restrict__ W1, const float* __restrict__ W2,
                       unsigned short* __restrict__ W1t, unsigned short* __restrict__ W2t) {
    int id = blockIdx.x * blockDim.x + threadIdx.x;
    if (id < IN_DIM * HD) {                 // W1 [256][128], coalesced read
        int k = id >> 7, n = id & 127;
        W1t[n * IN_DIM + k] = f2bf(W1[id]);
    }
    if (id < 48 * HD) {                     // W2t [48][128], coalesced write
        int n = id >> 7, k = id & 127;
        float v = (n < NC) ? W2[k * NC + n] : 0.f;
        W2t[id] = f2bf(v);
    }
}

// ---------------------------------------------------------------------------
// MFMA GEMM1: ft1b = bf16( bf16(x) @ bf16(W1) ).  M=50000, K=256, N=128.
// BM=64, BN=128, BK=32, 4 waves (2x2), A+W double-buffered in LDS.
// ---------------------------------------------------------------------------
__global__ __launch_bounds__(256) void mfma1_k(const float* __restrict__ X,
                                               const unsigned short* __restrict__ W1t,
                                               unsigned short* __restrict__ ftb) {
    __shared__ unsigned short alds[2][64 * 32];    // 2x4KB
    __shared__ unsigned short wlds[2][128 * 32];   // 2x8KB
    const int tid = threadIdx.x;
    const int lane = tid & 63, wid = tid >> 6;
    const int wr = wid >> 1, wc = wid & 1;
    const int rowBase = blockIdx.x * 64;
    const int s_arow = tid >> 2, s_ac = tid & 3;   // A: 64 rows x 4 chunks
    const int s_wcol = tid >> 1, s_wc0 = (tid & 1) * 2;  // W: 128 cols, 2 chunks/thr

    auto stageA = [&](int buf, int ks) {
        float4 v0 = make_float4(0.f,0.f,0.f,0.f), v1 = v0;
        int gr = rowBase + s_arow;
        if (gr < N_NODES) {
            const float4* p = (const float4*)(X + (size_t)gr * IN_DIM + ks * 32 + s_ac * 8);
            v0 = p[0]; v1 = p[1];
        }
        *(uint4*)&alds[buf][tile32_addr(s_arow, s_ac)] =
            pack8(v0.x,v0.y,v0.z,v0.w,v1.x,v1.y,v1.z,v1.w);
    };
    auto stageW = [&](int buf, int ks) {
        const uint4* g = (const uint4*)(W1t + s_wcol * IN_DIM + ks * 32 + s_wc0 * 8);
        uint4 a = g[0], b = g[1];
        *(uint4*)&wlds[buf][tile32_addr(s_wcol, s_wc0)] = a;
        *(uint4*)&wlds[buf][tile32_addr(s_wcol, s_wc0 + 1)] = b;
    };

    f32x4 acc[2][4];
    #pragma unroll
    for (int mf = 0; mf < 2; ++mf)
        #pragma unroll
        for (int nf = 0; nf < 4; ++nf)
            acc[mf][nf] = (f32x4){0.f, 0.f, 0.f, 0.f};

    stageA(0, 0); stageW(0, 0);
    for (int ks = 0; ks < 8; ++ks) {
        __syncthreads();                       // staging for buf(ks) complete
        if (ks < 7) { stageA((ks + 1) & 1, ks + 1); stageW((ks + 1) & 1, ks + 1); }
        int buf = ks & 1;
        bf16x8 afrag[2], bfrag[4];
        #pragma unroll
        for (int mf = 0; mf < 2; ++mf) {
            int row = wr * 32 + mf * 16 + (lane & 15);
            afrag[mf] = *(const bf16x8*)&alds[buf][tile32_addr(row, lane >> 4)];
        }
        #pragma unroll
        for (int nf = 0; nf < 4; ++nf) {
            int col = wc * 64 + nf * 16 + (lane & 15);
            bfrag[nf] = *(const bf16x8*)&wlds[buf][tile32_addr(col, lane >> 4)];
        }
        #pragma unroll
        for (int mf = 0; mf < 2; ++mf)
            #pragma unroll
            for (int nf = 0; nf < 4; ++nf)
                acc[mf][nf] = __builtin_amdgcn_mfma_f32_16x16x32_bf16(
                    afrag[mf], bfrag[nf], acc[mf][nf], 0, 0, 0);
    }
    #pragma unroll
    for (int mf = 0; mf < 2; ++mf) {
        int r0 = rowBase + wr * 32 + mf * 16 + (lane >> 4) * 4;
        #pragma unroll
        for (int nf = 0; nf < 4; ++nf) {
            int col = wc * 64 + nf * 16 + (lane & 15);
            #pragma unroll
            for (int v = 0; v < 4; ++v) {
                int r = r0 + v;
                if (r < N_NODES) ftb[(size_t)r * HD + col] = f2bf(acc[mf][nf][v]);
            }
        }
    }
}

// ---------------------------------------------------------------------------
// MFMA GEMM2: ft2b = bf16( elu(bn(h1)) @ W2 ).  M=50000, K=128, N=40(pad 48).
// BM=64, 4 waves x 16 rows, BK=32. W2t resident in LDS; A double-buffered
// with BN+ELU+cvt fused on staging.
// ---------------------------------------------------------------------------
__global__ __launch_bounds__(256) void mfma2_k(const float* __restrict__ Hin,
                                               const unsigned short* __restrict__ W2t,
                                               const float* __restrict__ scale,
                                               const float* __restrict__ shift,
                                               unsigned short* __restrict__ ft2b) {
    __shared__ unsigned short alds[2][64 * 32];    // 2x4KB
    __shared__ unsigned short wlds[48 * 128];      // 12KB, pos = c ^ (col&7)
    const int tid = threadIdx.x;
    const int lane = tid & 63, wid = tid >> 6;
    const int rowBase = blockIdx.x * 64;
    const int s_arow = tid >> 2, s_ac = tid & 3;

    for (int i = tid; i < 48 * 16; i += 256) {     // W2t -> LDS (once)
        int col = i >> 4, c = i & 15;
        uint4 v = *(const uint4*)(W2t + col * HD + c * 8);
        *(uint4*)&wlds[col * HD + ((c ^ (col & 7)) << 3)] = v;
    }

    auto stageA = [&](int buf, int ks) {
        int c0 = ks * 32 + s_ac * 8;
        float4 v0 = make_float4(0.f,0.f,0.f,0.f), v1 = v0;
        int gr = rowBase + s_arow;
        if (gr < N_NODES) {
            const float4* p = (const float4*)(Hin + (size_t)gr * HD + c0);
            v0 = p[0]; v1 = p[1];
        }
        float4 sc0 = *(const float4*)(scale + c0), sc1 = *(const float4*)(scale + c0 + 4);
        float4 sh0 = *(const float4*)(shift + c0), sh1 = *(const float4*)(shift + c0 + 4);
        float t[8];
        t[0] = fmaf(v0.x, sc0.x, sh0.x); t[1] = fmaf(v0.y, sc0.y, sh0.y);
        t[2] = fmaf(v0.z, sc0.z, sh0.z); t[3] = fmaf(v0.w, sc0.w, sh0.w);
        t[4] = fmaf(v1.x, sc1.x, sh1.x); t[5] = fmaf(v1.y, sc1.y, sh1.y);
        t[6] = fmaf(v1.z, sc1.z, sh1.z); t[7] = fmaf(v1.w, sc1.w, sh1.w);
        #pragma unroll
        for (int i = 0; i < 8; ++i) t[i] = t[i] > 0.f ? t[i] : expm1f(t[i]);
        *(uint4*)&alds[buf][tile32_addr(s_arow, s_ac)] =
            pack8(t[0],t[1],t[2],t[3],t[4],t[5],t[6],t[7]);
    };

    f32x4 acc[3];
    #pragma unroll
    for (int nf = 0; nf < 3; ++nf) acc[nf] = (f32x4){0.f, 0.f, 0.f, 0.f};

    stageA(0, 0);
    for (int ks = 0; ks < 4; ++ks) {
        __syncthreads();
        if (ks < 3) stageA((ks + 1) & 1, ks + 1);
        int buf = ks & 1;
        int row = wid * 16 + (lane & 15);
        bf16x8 a = *(const bf16x8*)&alds[buf][tile32_addr(row, lane >> 4)];
        #pragma unroll
        for (int nf = 0; nf < 3; ++nf) {
            int col = nf * 16 + (lane & 15);
            int c = ks * 4 + (lane >> 4);
            bf16x8 b = *(const bf16x8*)&wlds[col * HD + ((c ^ (col & 7)) << 3)];
            acc[nf] = __builtin_amdgcn_mfma_f32_16x16x32_bf16(a, b, acc[nf], 0, 0, 0);
        }
    }
    int r0 = rowBase + wid * 16 + (lane >> 4) * 4;
    #pragma unroll
    for (int nf = 0; nf < 3; ++nf) {
        int col = nf * 16 + (lane & 15);
        if (col < NC) {
            #pragma unroll
            for (int v = 0; v < 4; ++v) {
                int r = r0 + v;
                if (r < N_NODES) ft2b[(size_t)r * NC + col] = f2bf(acc[nf][v]);
            }
        }
    }
}

// ---------------------------------------------------------------------------
// CSR build: histogram -> 2-level exclusive scan -> scatter with per-node cursor
// ---------------------------------------------------------------------------
__global__ void hist_k(const int* __restrict__ dst, int* __restrict__ cnt) {
    int e = blockIdx.x * blockDim.x + threadIdx.x;
    if (e < N_EDGES) atomicAdd(&cnt[dst[e]], 1);
}

__global__ void scan1_k(const int* __restrict__ cnt, int* __restrict__ rowpart,
                        int* __restrict__ bsum) {
    __shared__ int sh[256];
    int i = blockIdx.x * 256 + threadIdx.x;
    int v = (i < N_NODES) ? cnt[i] : 0;
    sh[threadIdx.x] = v;
    __syncthreads();
    #pragma unroll
    for (int off = 1; off < 256; off <<= 1) {
        int t = (threadIdx.x >= off) ? sh[threadIdx.x - off] : 0;
        __syncthreads();
        sh[threadIdx.x] += t;
        __syncthreads();
    }
    if (i < N_NODES) rowpart[i] = sh[threadIdx.x] - v;   // exclusive
    if (threadIdx.x == 255) bsum[blockIdx.x] = sh[255];
}

__global__ void scan2_k(int* __restrict__ bsum, int nb) {
    __shared__ int sh[256];
    int v = (threadIdx.x < nb) ? bsum[threadIdx.x] : 0;
    sh[threadIdx.x] = v;
    __syncthreads();
    #pragma unroll
    for (int off = 1; off < 256; off <<= 1) {
        int t = (threadIdx.x >= off) ? sh[threadIdx.x - off] : 0;
        __syncthreads();
        sh[threadIdx.x] += t;
        __syncthreads();
    }
    bsum[threadIdx.x] = sh[threadIdx.x] - v;
}

__global__ void scan3_k(const int* __restrict__ rowpart, const int* __restrict__ bsum,
                        int* __restrict__ row) {
    int i = blockIdx.x * blockDim.x + threadIdx.x;
    if (i < N_NODES) row[i] = rowpart[i] + bsum[i >> 8];
    if (i == N_NODES) row[N_NODES] = N_EDGES;
}

__global__ void scatter_k(const int* __restrict__ src, const int* __restrict__ dst,
                          const int* __restrict__ row, int* __restrict__ cursor,
                          int* __restrict__ csr_src) {
    int e = blockIdx.x * blockDim.x + threadIdx.x;
    if (e >= N_EDGES) return;
    int v = dst[e];
    int slot = row[v] + atomicAdd(&cursor[v], 1);
    csr_src[slot] = src[e];
}

// ---------------------------------------------------------------------------
// el/er layer 1 from bf16 features: one thread per (node, head)
// ---------------------------------------------------------------------------
__global__ void eler1b_k(const unsigned short* __restrict__ ftb,
                         const float* __restrict__ alw, const float* __restrict__ arw,
                         float* __restrict__ el, float* __restrict__ er) {
    int t = blockIdx.x * blockDim.x + threadIdx.x;
    if (t >= N_NODES * H1) return;
    int n = t >> 2, h = t & 3;
    const unsigned short* f = ftb + (size_t)n * HD + h * D;
    const float* a = alw + h * D;
    const float* r = arw + h * D;
    float sl = 0.f, sr = 0.f;
    #pragma unroll
    for (int d = 0; d < D; d += 8) {
        uint4 fv = *(const uint4*)(f + d);
        float x0 = bf2f(fv.x & 0xffff), x1 = bf2f(fv.x >> 16);
        float x2 = bf2f(fv.y & 0xffff), x3 = bf2f(fv.y >> 16);
        float x4 = bf2f(fv.z & 0xffff), x5 = bf2f(fv.z >> 16);
        float x6 = bf2f(fv.w & 0xffff), x7 = bf2f(fv.w >> 16);
        sl += x0*a[d] + x1*a[d+1] + x2*a[d+2] + x3*a[d+3]
            + x4*a[d+4] + x5*a[d+5] + x6*a[d+6] + x7*a[d+7];
        sr += x0*r[d] + x1*r[d+1] + x2*r[d+2] + x3*r[d+3]
            + x4*r[d+4] + x5*r[d+5] + x6*r[d+6] + x7*r[d+7];
    }
    el[t] = sl; er[t] = sr;
}

// ---------------------------------------------------------------------------
// layer-1 gather: one wave per dst node; lane owns bf16x2 of the 128 dims.
// ---------------------------------------------------------------------------
__global__ __launch_bounds__(256) void gather1_k(const int* __restrict__ row,
                                                 const int* __restrict__ csr_src,
                                                 const unsigned short* __restrict__ ftb,
                                                 const float* __restrict__ el,
                                                 const float* __restrict__ er,
                                                 float* __restrict__ h1) {
    int w = (blockIdx.x * blockDim.x + threadIdx.x) >> 6;   // node
    if (w >= N_NODES) return;
    int lane = threadIdx.x & 63;
    int hh = lane >> 4;
    float erv = er[w * H1 + hh];
    int jb = row[w], je = row[w + 1];
    float ax = 0.f, ay = 0.f, ssum = 0.f;
    int j = jb;
    for (; j + 1 < je; j += 2) {
        int u0 = csr_src[j], u1 = csr_src[j + 1];
        float e0 = el[u0 * H1 + hh] + erv;
        float e1 = el[u1 * H1 + hh] + erv;
        e0 = e0 > 0.f ? e0 : SLOPE * e0;
        e1 = e1 > 0.f ? e1 : SLOPE * e1;
        float x0 = __expf(e0), x1 = __expf(e1);
        ushort2 f0 = *(const ushort2*)(ftb + (size_t)u0 * HD + lane * 2);
        ushort2 f1 = *(const ushort2*)(ftb + (size_t)u1 * HD + lane * 2);
        ax = fmaf(x0, bf2f(f0.x), ax); ay = fmaf(x0, bf2f(f0.y), ay);
        ax = fmaf(x1, bf2f(f1.x), ax); ay = fmaf(x1, bf2f(f1.y), ay);
        ssum += x0 + x1;
    }
    if (j < je) {
        int u0 = csr_src[j];
        float e0 = el[u0 * H1 + hh] + erv;
        e0 = e0 > 0.f ? e0 : SLOPE * e0;
        float x0 = __expf(e0);
        ushort2 f0 = *(const ushort2*)(ftb + (size_t)u0 * HD + lane * 2);
        ax = fmaf(x0, bf2f(f0.x), ax); ay = fmaf(x0, bf2f(f0.y), ay);
        ssum += x0;
    }
    float inv = 1.0f / fmaxf(ssum, 1e-9f);
    *(float2*)(h1 + (size_t)w * HD + lane * 2) = make_float2(ax * inv, ay * inv);
}

// ---------------------------------------------------------------------------
// BN stats on raw h1; fold to per-column scale/shift
// ---------------------------------------------------------------------------
__global__ void bnstats_k(const float* __restrict__ h1,
                          float* __restrict__ sums, float* __restrict__ sumsq) {
    int c = threadIdx.x;  // 128 threads
    float acc = 0.f, acc2 = 0.f;
    for (int r = blockIdx.x; r < N_NODES; r += gridDim.x) {
        float v = h1[(size_t)r * HD + c];
        acc += v; acc2 += v * v;
    }
    atomicAdd(&sums[c], acc);
    atomicAdd(&sumsq[c], acc2);
}

__global__ void bnscale_k(const float* __restrict__ sums, const float* __restrict__ sumsq,
                          const float* __restrict__ gamma, const float* __restrict__ beta,
                          float* __restrict__ scale, float* __restrict__ shift) {
    int c = threadIdx.x;  // 128
    const float invN = 1.0f / (float)N_NODES;
    float mu = sums[c] * invN;
    float var = sumsq[c] * invN - mu * mu;
    float sc = gamma[c] * rsqrtf(var + EPS_BN);
    scale[c] = sc;
    shift[c] = beta[c] - mu * sc;
}

// el/er for layer 2 from bf16 ft2: one thread per node, 40-dim dot
__global__ void eler2b_k(const unsigned short* __restrict__ ft2b,
                         const float* __restrict__ alw, const float* __restrict__ arw,
                         float* __restrict__ el, float* __restrict__ er) {
    int n = blockIdx.x * blockDim.x + threadIdx.x;
    if (n >= N_NODES) return;
    const unsigned short* f = ft2b + (size_t)n * NC;
    float sl = 0.f, sr = 0.f;
    #pragma unroll
    for (int d = 0; d < NC; d += 4) {
        uint2 fv = *(const uint2*)(f + d);     // 8B aligned (80B rows)
        float x0 = bf2f(fv.x & 0xffff), x1 = bf2f(fv.x >> 16);
        float x2 = bf2f(fv.y & 0xffff), x3 = bf2f(fv.y >> 16);
        sl += x0*alw[d] + x1*alw[d+1] + x2*alw[d+2] + x3*alw[d+3];
        sr += x0*arw[d] + x1*arw[d+1] + x2*arw[d+2] + x3*arw[d+3];
    }
    el[n] = sl; er[n] = sr;
}

// ---------------------------------------------------------------------------
// layer-2 gather fused with log_softmax
// ---------------------------------------------------------------------------
__global__ __launch_bounds__(256) void gather2_k(const int* __restrict__ row,
                                                 const int* __restrict__ csr_src,
                                                 const unsigned short* __restrict__ ft2b,
                                                 const float* __restrict__ el,
                                                 const float* __restrict__ er,
                                                 float* __restrict__ out) {
    int w = (blockIdx.x * blockDim.x + threadIdx.x) >> 6;   // node
    if (w >= N_NODES) return;
    int lane = threadIdx.x & 63;
    float erv = er[w];
    int jb = row[w], je = row[w + 1];
    float acc = 0.f, ssum = 0.f;
    int j = jb;
    for (; j + 1 < je; j += 2) {
        int u0 = csr_src[j], u1 = csr_src[j + 1];
        float e0 = el[u0] + erv, e1 = el[u1] + erv;
        e0 = e0 > 0.f ? e0 : SLOPE * e0;
        e1 = e1 > 0.f ? e1 : SLOPE * e1;
        float x0 = __expf(e0), x1 = __expf(e1);
        float fa = (lane < NC) ? bf2f(ft2b[(size_t)u0 * NC + lane]) : 0.f;
        float fb = (lane < NC) ? bf2f(ft2b[(size_t)u1 * NC + lane]) : 0.f;
        acc = fmaf(x0, fa, acc);
        acc = fmaf(x1, fb, acc);
        ssum += x0 + x1;
    }
    if (j < je) {
        int u0 = csr_src[j];
        float e0 = el[u0] + erv;
        e0 = e0 > 0.f ? e0 : SLOPE * e0;
        float x0 = __expf(e0);
        float fa = (lane < NC) ? bf2f(ft2b[(size_t)u0 * NC + lane]) : 0.f;
        acc = fmaf(x0, fa, acc);
        ssum += x0;
    }
    float v = acc / fmaxf(ssum, 1e-9f);
    float vv = (lane < NC) ? v : -INFINITY;
    float m = vv;
    #pragma unroll
    for (int off = 32; off; off >>= 1) m = fmaxf(m, __shfl_xor(m, off));
    float ex2 = (lane < NC) ? __expf(vv - m) : 0.f;
    float sum = ex2;
    #pragma unroll
    for (int off = 32; off; off >>= 1) sum += __shfl_xor(sum, off);
    if (lane < NC) out[(size_t)w * NC + lane] = vv - m - logf(sum);
}

// ---------------------------------------------------------------------------
extern "C" void kernel_launch(void* const* d_in, const int* in_sizes, int n_in,
                              void* d_out, int out_size, void* d_ws, size_t ws_size,
                              hipStream_t stream) {
    const float* x     = (const float*)d_in[0];
    const int*   src   = (const int*)  d_in[1];
    const int*   dst   = (const int*)  d_in[2];
    const float* W1    = (const float*)d_in[3];
    const float* al1   = (const float*)d_in[4];
    const float* ar1   = (const float*)d_in[5];
    const float* gamma = (const float*)d_in[6];
    const float* beta  = (const float*)d_in[7];
    const float* W2    = (const float*)d_in[8];
    const float* al2   = (const float*)d_in[9];
    const float* ar2   = (const float*)d_in[10];
    float* out = (float*)d_out;

    char* ws = (char*)d_ws;
    size_t o = 0;
    auto allocB = [&](size_t bytes) { void* p = ws + o; o += (bytes + 15) & ~15ull; return p; };
    // ---- zeroed region (one small memset) ----
    int*   cnt    = (int*)allocB(N_NODES * 4);
    int*   cursor = (int*)allocB(N_NODES * 4);
    float* bnsum  = (float*)allocB(HD * 4);
    float* bnsq   = (float*)allocB(HD * 4);
    size_t zeroBytes = o;
    // ---- uninitialized region ----
    int*   rowpart = (int*)allocB(N_NODES * 4);
    int*   bsum    = (int*)allocB(256 * 4);
    int*   rowp    = (int*)allocB((N_NODES + 1) * 4);
    int*   csr_src = (int*)allocB(N_EDGES * 4);
    unsigned short* w1t  = (unsigned short*)allocB((size_t)IN_DIM * HD * 2);
    unsigned short* w2t  = (unsigned short*)allocB((size_t)48 * HD * 2);
    unsigned short* ft1b = (unsigned short*)allocB((size_t)N_NODES * HD * 2);
    float* h1   = (float*)allocB((size_t)N_NODES * HD * 4);
    float* el1  = (float*)allocB(N_NODES * H1 * 4);
    float* er1  = (float*)allocB(N_NODES * H1 * 4);
    unsigned short* ft2b = (unsigned short*)allocB((size_t)N_NODES * NC * 2);
    float* el2  = (float*)allocB(N_NODES * 4);
    float* er2  = (float*)allocB(N_NODES * 4);
    float* bnscale = (float*)allocB(HD * 4);
    float* bnshift = (float*)allocB(HD * 4);

    hipMemsetAsync(d_ws, 0, zeroBytes, stream);

    const int NB_SCAN = (N_NODES + 255) / 256;            // 196
    const int NB_E    = (N_EDGES + 255) / 256;            // 3321
    const int NB_G    = (N_NODES + 63) / 64;              // 782 (BM=64 tiles)

    // weight prep + CSR build
    cvtw_k   <<<(IN_DIM * HD + 255) / 256, 256, 0, stream>>>(W1, W2, w1t, w2t);
    hist_k   <<<NB_E, 256, 0, stream>>>(dst, cnt);
    scan1_k  <<<NB_SCAN, 256, 0, stream>>>(cnt, rowpart, bsum);
    scan2_k  <<<1, 256, 0, stream>>>(bsum, NB_SCAN);
    scan3_k  <<<(N_NODES + 256) / 256 + 1, 256, 0, stream>>>(rowpart, bsum, rowp);
    scatter_k<<<NB_E, 256, 0, stream>>>(src, dst, rowp, cursor, csr_src);

    // layer 1
    mfma1_k<<<NB_G, 256, 0, stream>>>(x, w1t, ft1b);
    eler1b_k<<<(N_NODES * H1 + 255) / 256, 256, 0, stream>>>(ft1b, al1, ar1, el1, er1);
    gather1_k<<<N_NODES / 4, 256, 0, stream>>>(rowp, csr_src, ft1b, el1, er1, h1);

    bnstats_k<<<512, HD, 0, stream>>>(h1, bnsum, bnsq);
    bnscale_k<<<1, HD, 0, stream>>>(bnsum, bnsq, gamma, beta, bnscale, bnshift);

    // layer 2 (BN+ELU fused into GEMM2 A-staging)
    mfma2_k<<<NB_G, 256, 0, stream>>>(h1, w2t, bnscale, bnshift, ft2b);
    eler2b_k<<<(N_NODES + 255) / 256, 256, 0, stream>>>(ft2b, al2, ar2, el2, er2);
    gather2_k<<<N_NODES / 4, 256, 0, stream>>>(rowp, csr_src, ft2b, el2, er2, out);
}

// Round 5
// 394.491 us; speedup vs baseline: 5.7754x; 1.0058x over previous
//
#include <hip/hip_runtime.h>
#include <hip/hip_bf16.h>
#include <math.h>

#define N_NODES 50000
#define N_EDGES 850000
#define IN_DIM  256
#define HD      128      // H1*D
#define H1      4
#define D       32
#define NC      40       // num classes
#define SLOPE   0.2f
#define EPS_BN  1e-5f

typedef __attribute__((ext_vector_type(8))) short bf16x8;
typedef __attribute__((ext_vector_type(4))) float f32x4;

__device__ __forceinline__ unsigned short f2bf(float x) {
    union { float f; unsigned u; } v; v.f = x;
    unsigned r = v.u + 0x7FFF + ((v.u >> 16) & 1);   // RNE
    return (unsigned short)(r >> 16);
}
__device__ __forceinline__ float bf2f(unsigned short h) {
    union { unsigned u; float f; } v; v.u = ((unsigned)h) << 16;
    return v.f;
}
__device__ __forceinline__ uint4 pack8(float a0,float a1,float a2,float a3,
                                       float a4,float a5,float a6,float a7) {
    uint4 p;
    p.x = f2bf(a0) | ((unsigned)f2bf(a1) << 16);
    p.y = f2bf(a2) | ((unsigned)f2bf(a3) << 16);
    p.z = f2bf(a4) | ((unsigned)f2bf(a5) << 16);
    p.w = f2bf(a6) | ((unsigned)f2bf(a7) << 16);
    return p;
}

// chunk-swizzled [rows][32] bf16 tile: 4 chunks of 8 bf16 per row (64B rows).
__device__ __forceinline__ int tile32_addr(int row, int chunk) {
    return row * 32 + ((chunk ^ ((row >> 1) & 3)) << 3);
}

// ---------------------------------------------------------------------------
// Weight prep: W1t bf16 [128][256] = W1^T; W2t bf16 [48][128] = W2^T (pad 0)
// ---------------------------------------------------------------------------
__global__ void cvtw_k(const float* __restrict__ W1, const float* __restrict__ W2,
                       unsigned short* __restrict__ W1t, unsigned short* __restrict__ W2t) {
    int id = blockIdx.x * blockDim.x + threadIdx.x;
    if (id < IN_DIM * HD) {                 // W1 [256][128], coalesced read
        int k = id >> 7, n = id & 127;
        W1t[n * IN_DIM + k] = f2bf(W1[id]);
    }
    if (id < 48 * HD) {                     // W2t [48][128], coalesced write
        int n = id >> 7, k = id & 127;
        float v = (n < NC) ? W2[k * NC + n] : 0.f;
        W2t[id] = f2bf(v);
    }
}

// ---------------------------------------------------------------------------
// MFMA GEMM1: ft1b = bf16( bf16(x) @ bf16(W1) ).  M=50000, K=256, N=128.
// ---------------------------------------------------------------------------
__global__ __launch_bounds__(256) void mfma1_k(const float* __restrict__ X,
                                               const unsigned short* __restrict__ W1t,
                                               unsigned short* __restrict__ ftb) {
    __shared__ unsigned short alds[2][64 * 32];
    __shared__ unsigned short wlds[2][128 * 32];
    const int tid = threadIdx.x;
    const int lane = tid & 63, wid = tid >> 6;
    const int wr = wid >> 1, wc = wid & 1;
    const int rowBase = blockIdx.x * 64;
    const int s_arow = tid >> 2, s_ac = tid & 3;
    const int s_wcol = tid >> 1, s_wc0 = (tid & 1) * 2;

    auto stageA = [&](int buf, int ks) {
        float4 v0 = make_float4(0.f,0.f,0.f,0.f), v1 = v0;
        int gr = rowBase + s_arow;
        if (gr < N_NODES) {
            const float4* p = (const float4*)(X + (size_t)gr * IN_DIM + ks * 32 + s_ac * 8);
            v0 = p[0]; v1 = p[1];
        }
        *(uint4*)&alds[buf][tile32_addr(s_arow, s_ac)] =
            pack8(v0.x,v0.y,v0.z,v0.w,v1.x,v1.y,v1.z,v1.w);
    };
    auto stageW = [&](int buf, int ks) {
        const uint4* g = (const uint4*)(W1t + s_wcol * IN_DIM + ks * 32 + s_wc0 * 8);
        uint4 a = g[0], b = g[1];
        *(uint4*)&wlds[buf][tile32_addr(s_wcol, s_wc0)] = a;
        *(uint4*)&wlds[buf][tile32_addr(s_wcol, s_wc0 + 1)] = b;
    };

    f32x4 acc[2][4];
    #pragma unroll
    for (int mf = 0; mf < 2; ++mf)
        #pragma unroll
        for (int nf = 0; nf < 4; ++nf)
            acc[mf][nf] = (f32x4){0.f, 0.f, 0.f, 0.f};

    stageA(0, 0); stageW(0, 0);
    for (int ks = 0; ks < 8; ++ks) {
        __syncthreads();
        if (ks < 7) { stageA((ks + 1) & 1, ks + 1); stageW((ks + 1) & 1, ks + 1); }
        int buf = ks & 1;
        bf16x8 afrag[2], bfrag[4];
        #pragma unroll
        for (int mf = 0; mf < 2; ++mf) {
            int row = wr * 32 + mf * 16 + (lane & 15);
            afrag[mf] = *(const bf16x8*)&alds[buf][tile32_addr(row, lane >> 4)];
        }
        #pragma unroll
        for (int nf = 0; nf < 4; ++nf) {
            int col = wc * 64 + nf * 16 + (lane & 15);
            bfrag[nf] = *(const bf16x8*)&wlds[buf][tile32_addr(col, lane >> 4)];
        }
        #pragma unroll
        for (int mf = 0; mf < 2; ++mf)
            #pragma unroll
            for (int nf = 0; nf < 4; ++nf)
                acc[mf][nf] = __builtin_amdgcn_mfma_f32_16x16x32_bf16(
                    afrag[mf], bfrag[nf], acc[mf][nf], 0, 0, 0);
    }
    #pragma unroll
    for (int mf = 0; mf < 2; ++mf) {
        int r0 = rowBase + wr * 32 + mf * 16 + (lane >> 4) * 4;
        #pragma unroll
        for (int nf = 0; nf < 4; ++nf) {
            int col = wc * 64 + nf * 16 + (lane & 15);
            #pragma unroll
            for (int v = 0; v < 4; ++v) {
                int r = r0 + v;
                if (r < N_NODES) ftb[(size_t)r * HD + col] = f2bf(acc[mf][nf][v]);
            }
        }
    }
}

// ---------------------------------------------------------------------------
// MFMA GEMM2: ft2b = bf16( elu(bn(h1b)) @ W2 ).  M=50000, K=128, N=40(pad 48).
// A staged from bf16 h1 with BN+ELU fused.
// ---------------------------------------------------------------------------
__global__ __launch_bounds__(256) void mfma2_k(const unsigned short* __restrict__ Hin,
                                               const unsigned short* __restrict__ W2t,
                                               const float* __restrict__ scale,
                                               const float* __restrict__ shift,
                                               unsigned short* __restrict__ ft2b) {
    __shared__ unsigned short alds[2][64 * 32];
    __shared__ unsigned short wlds[48 * 128];
    const int tid = threadIdx.x;
    const int lane = tid & 63, wid = tid >> 6;
    const int rowBase = blockIdx.x * 64;
    const int s_arow = tid >> 2, s_ac = tid & 3;

    for (int i = tid; i < 48 * 16; i += 256) {
        int col = i >> 4, c = i & 15;
        uint4 v = *(const uint4*)(W2t + col * HD + c * 8);
        *(uint4*)&wlds[col * HD + ((c ^ (col & 7)) << 3)] = v;
    }

    auto stageA = [&](int buf, int ks) {
        int c0 = ks * 32 + s_ac * 8;
        uint4 pv = make_uint4(0,0,0,0);
        int gr = rowBase + s_arow;
        if (gr < N_NODES) pv = *(const uint4*)(Hin + (size_t)gr * HD + c0);
        float4 sc0 = *(const float4*)(scale + c0), sc1 = *(const float4*)(scale + c0 + 4);
        float4 sh0 = *(const float4*)(shift + c0), sh1 = *(const float4*)(shift + c0 + 4);
        float t[8];
        t[0] = fmaf(bf2f(pv.x & 0xffff), sc0.x, sh0.x);
        t[1] = fmaf(bf2f(pv.x >> 16),    sc0.y, sh0.y);
        t[2] = fmaf(bf2f(pv.y & 0xffff), sc0.z, sh0.z);
        t[3] = fmaf(bf2f(pv.y >> 16),    sc0.w, sh0.w);
        t[4] = fmaf(bf2f(pv.z & 0xffff), sc1.x, sh1.x);
        t[5] = fmaf(bf2f(pv.z >> 16),    sc1.y, sh1.y);
        t[6] = fmaf(bf2f(pv.w & 0xffff), sc1.z, sh1.z);
        t[7] = fmaf(bf2f(pv.w >> 16),    sc1.w, sh1.w);
        #pragma unroll
        for (int i = 0; i < 8; ++i) t[i] = t[i] > 0.f ? t[i] : expm1f(t[i]);
        *(uint4*)&alds[buf][tile32_addr(s_arow, s_ac)] =
            pack8(t[0],t[1],t[2],t[3],t[4],t[5],t[6],t[7]);
    };

    f32x4 acc[3];
    #pragma unroll
    for (int nf = 0; nf < 3; ++nf) acc[nf] = (f32x4){0.f, 0.f, 0.f, 0.f};

    stageA(0, 0);
    for (int ks = 0; ks < 4; ++ks) {
        __syncthreads();
        if (ks < 3) stageA((ks + 1) & 1, ks + 1);
        int buf = ks & 1;
        int row = wid * 16 + (lane & 15);
        bf16x8 a = *(const bf16x8*)&alds[buf][tile32_addr(row, lane >> 4)];
        #pragma unroll
        for (int nf = 0; nf < 3; ++nf) {
            int col = nf * 16 + (lane & 15);
            int c = ks * 4 + (lane >> 4);
            bf16x8 b = *(const bf16x8*)&wlds[col * HD + ((c ^ (col & 7)) << 3)];
            acc[nf] = __builtin_amdgcn_mfma_f32_16x16x32_bf16(a, b, acc[nf], 0, 0, 0);
        }
    }
    int r0 = rowBase + wid * 16 + (lane >> 4) * 4;
    #pragma unroll
    for (int nf = 0; nf < 3; ++nf) {
        int col = nf * 16 + (lane & 15);
        if (col < NC) {
            #pragma unroll
            for (int v = 0; v < 4; ++v) {
                int r = r0 + v;
                if (r < N_NODES) ft2b[(size_t)r * NC + col] = f2bf(acc[nf][v]);
            }
        }
    }
}

// ---------------------------------------------------------------------------
// CSR build
// ---------------------------------------------------------------------------
__global__ void hist_k(const int* __restrict__ dst, int* __restrict__ cnt) {
    int e = blockIdx.x * blockDim.x + threadIdx.x;
    if (e < N_EDGES) atomicAdd(&cnt[dst[e]], 1);
}

__global__ void scan1_k(const int* __restrict__ cnt, int* __restrict__ rowpart,
                        int* __restrict__ bsum) {
    __shared__ int sh[256];
    int i = blockIdx.x * 256 + threadIdx.x;
    int v = (i < N_NODES) ? cnt[i] : 0;
    sh[threadIdx.x] = v;
    __syncthreads();
    #pragma unroll
    for (int off = 1; off < 256; off <<= 1) {
        int t = (threadIdx.x >= off) ? sh[threadIdx.x - off] : 0;
        __syncthreads();
        sh[threadIdx.x] += t;
        __syncthreads();
    }
    if (i < N_NODES) rowpart[i] = sh[threadIdx.x] - v;   // exclusive
    if (threadIdx.x == 255) bsum[blockIdx.x] = sh[255];
}

__global__ void scan2_k(int* __restrict__ bsum, int nb) {
    __shared__ int sh[256];
    int v = (threadIdx.x < nb) ? bsum[threadIdx.x] : 0;
    sh[threadIdx.x] = v;
    __syncthreads();
    #pragma unroll
    for (int off = 1; off < 256; off <<= 1) {
        int t = (threadIdx.x >= off) ? sh[threadIdx.x - off] : 0;
        __syncthreads();
        sh[threadIdx.x] += t;
        __syncthreads();
    }
    bsum[threadIdx.x] = sh[threadIdx.x] - v;
}

__global__ void scan3_k(const int* __restrict__ rowpart, const int* __restrict__ bsum,
                        int* __restrict__ row) {
    int i = blockIdx.x * blockDim.x + threadIdx.x;
    if (i < N_NODES) row[i] = rowpart[i] + bsum[i >> 8];
    if (i == N_NODES) row[N_NODES] = N_EDGES;
}

__global__ void scatter_k(const int* __restrict__ src, const int* __restrict__ dst,
                          const int* __restrict__ row, int* __restrict__ cursor,
                          int* __restrict__ csr_src, int* __restrict__ csr_dst) {
    int e = blockIdx.x * blockDim.x + threadIdx.x;
    if (e >= N_EDGES) return;
    int v = dst[e];
    int slot = row[v] + atomicAdd(&cursor[v], 1);
    csr_src[slot] = src[e];
    csr_dst[slot] = v;
}

// ---------------------------------------------------------------------------
// el/er layer 1 from bf16 features
// ---------------------------------------------------------------------------
__global__ void eler1b_k(const unsigned short* __restrict__ ftb,
                         const float* __restrict__ alw, const float* __restrict__ arw,
                         float* __restrict__ el, float* __restrict__ er) {
    int t = blockIdx.x * blockDim.x + threadIdx.x;
    if (t >= N_NODES * H1) return;
    int n = t >> 2, h = t & 3;
    const unsigned short* f = ftb + (size_t)n * HD + h * D;
    const float* a = alw + h * D;
    const float* r = arw + h * D;
    float sl = 0.f, sr = 0.f;
    #pragma unroll
    for (int d = 0; d < D; d += 8) {
        uint4 fv = *(const uint4*)(f + d);
        float x0 = bf2f(fv.x & 0xffff), x1 = bf2f(fv.x >> 16);
        float x2 = bf2f(fv.y & 0xffff), x3 = bf2f(fv.y >> 16);
        float x4 = bf2f(fv.z & 0xffff), x5 = bf2f(fv.z >> 16);
        float x6 = bf2f(fv.w & 0xffff), x7 = bf2f(fv.w >> 16);
        sl += x0*a[d] + x1*a[d+1] + x2*a[d+2] + x3*a[d+3]
            + x4*a[d+4] + x5*a[d+5] + x6*a[d+6] + x7*a[d+7];
        sr += x0*r[d] + x1*r[d+1] + x2*r[d+2] + x3*r[d+3]
            + x4*r[d+4] + x5*r[d+5] + x6*r[d+6] + x7*r[d+7];
    }
    el[t] = sl; er[t] = sr;
}

// el/er for layer 2 from bf16 ft2
__global__ void eler2b_k(const unsigned short* __restrict__ ft2b,
                         const float* __restrict__ alw, const float* __restrict__ arw,
                         float* __restrict__ el, float* __restrict__ er) {
    int n = blockIdx.x * blockDim.x + threadIdx.x;
    if (n >= N_NODES) return;
    const unsigned short* f = ft2b + (size_t)n * NC;
    float sl = 0.f, sr = 0.f;
    #pragma unroll
    for (int d = 0; d < NC; d += 4) {
        uint2 fv = *(const uint2*)(f + d);
        float x0 = bf2f(fv.x & 0xffff), x1 = bf2f(fv.x >> 16);
        float x2 = bf2f(fv.y & 0xffff), x3 = bf2f(fv.y >> 16);
        sl += x0*alw[d] + x1*alw[d+1] + x2*alw[d+2] + x3*alw[d+3];
        sr += x0*arw[d] + x1*arw[d+1] + x2*arw[d+2] + x3*arw[d+3];
    }
    el[n] = sl; er[n] = sr;
}

// ---------------------------------------------------------------------------
// Edge-weight precompute (CSR order): exw1[e][h] / exw2[e]
// ---------------------------------------------------------------------------
__global__ void exw1_k(const int* __restrict__ csr_src, const int* __restrict__ csr_dst,
                       const float* __restrict__ el, const float* __restrict__ er,
                       float4* __restrict__ exw) {
    int e = blockIdx.x * blockDim.x + threadIdx.x;
    if (e >= N_EDGES) return;
    int u = csr_src[e], v = csr_dst[e];
    const float4 l = *(const float4*)(el + u * H1);
    const float4 r = *(const float4*)(er + v * H1);
    float4 o;
    float t;
    t = l.x + r.x; t = t > 0.f ? t : SLOPE * t; o.x = __expf(t);
    t = l.y + r.y; t = t > 0.f ? t : SLOPE * t; o.y = __expf(t);
    t = l.z + r.z; t = t > 0.f ? t : SLOPE * t; o.z = __expf(t);
    t = l.w + r.w; t = t > 0.f ? t : SLOPE * t; o.w = __expf(t);
    exw[e] = o;
}

__global__ void exw2_k(const int* __restrict__ csr_src, const int* __restrict__ csr_dst,
                       const float* __restrict__ el, const float* __restrict__ er,
                       float* __restrict__ exw) {
    int e = blockIdx.x * blockDim.x + threadIdx.x;
    if (e >= N_EDGES) return;
    float t = el[csr_src[e]] + er[csr_dst[e]];
    t = t > 0.f ? t : SLOPE * t;
    exw[e] = __expf(t);
}

// ---------------------------------------------------------------------------
// layer-1 gather: one wave per dst node; lane owns bf16x2 of 128 dims.
// Weights precomputed; unroll 4 for load-level parallelism. Writes bf16 h1.
// ---------------------------------------------------------------------------
__global__ __launch_bounds__(256) void gather1_k(const int* __restrict__ row,
                                                 const int* __restrict__ csr_src,
                                                 const float* __restrict__ exw,
                                                 const unsigned short* __restrict__ ftb,
                                                 unsigned int* __restrict__ h1b) {
    int w = (blockIdx.x * blockDim.x + threadIdx.x) >> 6;   // node
    if (w >= N_NODES) return;
    int lane = threadIdx.x & 63;
    int hh = lane >> 4;
    int jb = row[w], je = row[w + 1];
    float ax = 0.f, ay = 0.f, ssum = 0.f;
    int j = jb;
    for (; j + 3 < je; j += 4) {
        int u0 = csr_src[j], u1 = csr_src[j+1], u2 = csr_src[j+2], u3 = csr_src[j+3];
        float w0 = exw[(size_t)j*H1 + hh];
        float w1 = exw[(size_t)(j+1)*H1 + hh];
        float w2 = exw[(size_t)(j+2)*H1 + hh];
        float w3 = exw[(size_t)(j+3)*H1 + hh];
        ushort2 f0 = *(const ushort2*)(ftb + (size_t)u0 * HD + lane * 2);
        ushort2 f1 = *(const ushort2*)(ftb + (size_t)u1 * HD + lane * 2);
        ushort2 f2 = *(const ushort2*)(ftb + (size_t)u2 * HD + lane * 2);
        ushort2 f3 = *(const ushort2*)(ftb + (size_t)u3 * HD + lane * 2);
        ax = fmaf(w0, bf2f(f0.x), ax); ay = fmaf(w0, bf2f(f0.y), ay);
        ax = fmaf(w1, bf2f(f1.x), ax); ay = fmaf(w1, bf2f(f1.y), ay);
        ax = fmaf(w2, bf2f(f2.x), ax); ay = fmaf(w2, bf2f(f2.y), ay);
        ax = fmaf(w3, bf2f(f3.x), ax); ay = fmaf(w3, bf2f(f3.y), ay);
        ssum += (w0 + w1) + (w2 + w3);
    }
    for (; j < je; ++j) {
        int u0 = csr_src[j];
        float w0 = exw[(size_t)j*H1 + hh];
        ushort2 f0 = *(const ushort2*)(ftb + (size_t)u0 * HD + lane * 2);
        ax = fmaf(w0, bf2f(f0.x), ax); ay = fmaf(w0, bf2f(f0.y), ay);
        ssum += w0;
    }
    float inv = 1.0f / fmaxf(ssum, 1e-9f);
    h1b[(size_t)w * 64 + lane] = (unsigned)f2bf(ax * inv)
                               | ((unsigned)f2bf(ay * inv) << 16);
}

// ---------------------------------------------------------------------------
// BN stats on bf16 h1; fold to per-column scale/shift
// ---------------------------------------------------------------------------
__global__ void bnstats_k(const unsigned short* __restrict__ h1b,
                          float* __restrict__ sums, float* __restrict__ sumsq) {
    int c = threadIdx.x;  // 128 threads
    float acc = 0.f, acc2 = 0.f;
    for (int r = blockIdx.x; r < N_NODES; r += gridDim.x) {
        float v = bf2f(h1b[(size_t)r * HD + c]);
        acc += v; acc2 += v * v;
    }
    atomicAdd(&sums[c], acc);
    atomicAdd(&sumsq[c], acc2);
}

__global__ void bnscale_k(const float* __restrict__ sums, const float* __restrict__ sumsq,
                          const float* __restrict__ gamma, const float* __restrict__ beta,
                          float* __restrict__ scale, float* __restrict__ shift) {
    int c = threadIdx.x;  // 128
    const float invN = 1.0f / (float)N_NODES;
    float mu = sums[c] * invN;
    float var = sumsq[c] * invN - mu * mu;
    float sc = gamma[c] * rsqrtf(var + EPS_BN);
    scale[c] = sc;
    shift[c] = beta[c] - mu * sc;
}

// ---------------------------------------------------------------------------
// layer-2 gather fused with log_softmax; weights precomputed; unroll 4
// ---------------------------------------------------------------------------
__global__ __launch_bounds__(256) void gather2_k(const int* __restrict__ row,
                                                 const int* __restrict__ csr_src,
                                                 const float* __restrict__ exw,
                                                 const unsigned short* __restrict__ ft2b,
                                                 float* __restrict__ out) {
    int w = (blockIdx.x * blockDim.x + threadIdx.x) >> 6;   // node
    if (w >= N_NODES) return;
    int lane = threadIdx.x & 63;
    int jb = row[w], je = row[w + 1];
    float acc = 0.f, ssum = 0.f;
    int j = jb;
    for (; j + 3 < je; j += 4) {
        int u0 = csr_src[j], u1 = csr_src[j+1], u2 = csr_src[j+2], u3 = csr_src[j+3];
        float w0 = exw[j], w1 = exw[j+1], w2 = exw[j+2], w3 = exw[j+3];
        float fa = (lane < NC) ? bf2f(ft2b[(size_t)u0 * NC + lane]) : 0.f;
        float fb = (lane < NC) ? bf2f(ft2b[(size_t)u1 * NC + lane]) : 0.f;
        float fc = (lane < NC) ? bf2f(ft2b[(size_t)u2 * NC + lane]) : 0.f;
        float fd = (lane < NC) ? bf2f(ft2b[(size_t)u3 * NC + lane]) : 0.f;
        acc = fmaf(w0, fa, acc); acc = fmaf(w1, fb, acc);
        acc = fmaf(w2, fc, acc); acc = fmaf(w3, fd, acc);
        ssum += (w0 + w1) + (w2 + w3);
    }
    for (; j < je; ++j) {
        int u0 = csr_src[j];
        float w0 = exw[j];
        float fa = (lane < NC) ? bf2f(ft2b[(size_t)u0 * NC + lane]) : 0.f;
        acc = fmaf(w0, fa, acc);
        ssum += w0;
    }
    float v = acc / fmaxf(ssum, 1e-9f);
    float vv = (lane < NC) ? v : -INFINITY;
    float m = vv;
    #pragma unroll
    for (int off = 32; off; off >>= 1) m = fmaxf(m, __shfl_xor(m, off));
    float ex2 = (lane < NC) ? __expf(vv - m) : 0.f;
    float sum = ex2;
    #pragma unroll
    for (int off = 32; off; off >>= 1) sum += __shfl_xor(sum, off);
    if (lane < NC) out[(size_t)w * NC + lane] = vv - m - logf(sum);
}

// ---------------------------------------------------------------------------
extern "C" void kernel_launch(void* const* d_in, const int* in_sizes, int n_in,
                              void* d_out, int out_size, void* d_ws, size_t ws_size,
                              hipStream_t stream) {
    const float* x     = (const float*)d_in[0];
    const int*   src   = (const int*)  d_in[1];
    const int*   dst   = (const int*)  d_in[2];
    const float* W1    = (const float*)d_in[3];
    const float* al1   = (const float*)d_in[4];
    const float* ar1   = (const float*)d_in[5];
    const float* gamma = (const float*)d_in[6];
    const float* beta  = (const float*)d_in[7];
    const float* W2    = (const float*)d_in[8];
    const float* al2   = (const float*)d_in[9];
    const float* ar2   = (const float*)d_in[10];
    float* out = (float*)d_out;

    char* ws = (char*)d_ws;
    size_t o = 0;
    auto allocB = [&](size_t bytes) { void* p = ws + o; o += (bytes + 15) & ~15ull; return p; };
    // ---- zeroed region (one small memset) ----
    int*   cnt    = (int*)allocB(N_NODES * 4);
    int*   cursor = (int*)allocB(N_NODES * 4);
    float* bnsum  = (float*)allocB(HD * 4);
    float* bnsq   = (float*)allocB(HD * 4);
    size_t zeroBytes = o;
    // ---- uninitialized region ----
    int*   rowpart = (int*)allocB(N_NODES * 4);
    int*   bsum    = (int*)allocB(256 * 4);
    int*   rowp    = (int*)allocB((N_NODES + 1) * 4);
    int*   csr_src = (int*)allocB(N_EDGES * 4);
    int*   csr_dst = (int*)allocB(N_EDGES * 4);
    float4* exw1   = (float4*)allocB((size_t)N_EDGES * 16);
    float*  exw2   = (float*)allocB((size_t)N_EDGES * 4);
    unsigned short* w1t  = (unsigned short*)allocB((size_t)IN_DIM * HD * 2);
    unsigned short* w2t  = (unsigned short*)allocB((size_t)48 * HD * 2);
    unsigned short* ft1b = (unsigned short*)allocB((size_t)N_NODES * HD * 2);
    unsigned int*   h1b  = (unsigned int*)allocB((size_t)N_NODES * HD * 2);
    float* el1  = (float*)allocB(N_NODES * H1 * 4);
    float* er1  = (float*)allocB(N_NODES * H1 * 4);
    unsigned short* ft2b = (unsigned short*)allocB((size_t)N_NODES * NC * 2);
    float* el2  = (float*)allocB(N_NODES * 4);
    float* er2  = (float*)allocB(N_NODES * 4);
    float* bnscale = (float*)allocB(HD * 4);
    float* bnshift = (float*)allocB(HD * 4);

    hipMemsetAsync(d_ws, 0, zeroBytes, stream);

    const int NB_SCAN = (N_NODES + 255) / 256;            // 196
    const int NB_E    = (N_EDGES + 255) / 256;            // 3321
    const int NB_G    = (N_NODES + 63) / 64;              // 782

    // weight prep + CSR build
    cvtw_k   <<<(IN_DIM * HD + 255) / 256, 256, 0, stream>>>(W1, W2, w1t, w2t);
    hist_k   <<<NB_E, 256, 0, stream>>>(dst, cnt);
    scan1_k  <<<NB_SCAN, 256, 0, stream>>>(cnt, rowpart, bsum);
    scan2_k  <<<1, 256, 0, stream>>>(bsum, NB_SCAN);
    scan3_k  <<<(N_NODES + 256) / 256 + 1, 256, 0, stream>>>(rowpart, bsum, rowp);
    scatter_k<<<NB_E, 256, 0, stream>>>(src, dst, rowp, cursor, csr_src, csr_dst);

    // layer 1
    mfma1_k<<<NB_G, 256, 0, stream>>>(x, w1t, ft1b);
    eler1b_k<<<(N_NODES * H1 + 255) / 256, 256, 0, stream>>>(ft1b, al1, ar1, el1, er1);
    exw1_k<<<NB_E, 256, 0, stream>>>(csr_src, csr_dst, el1, er1, exw1);
    gather1_k<<<N_NODES / 4, 256, 0, stream>>>(rowp, csr_src, (const float*)exw1, ft1b, h1b);

    bnstats_k<<<512, HD, 0, stream>>>((const unsigned short*)h1b, bnsum, bnsq);
    bnscale_k<<<1, HD, 0, stream>>>(bnsum, bnsq, gamma, beta, bnscale, bnshift);

    // layer 2
    mfma2_k<<<NB_G, 256, 0, stream>>>((const unsigned short*)h1b, w2t, bnscale, bnshift, ft2b);
    eler2b_k<<<(N_NODES + 255) / 256, 256, 0, stream>>>(ft2b, al2, ar2, el2, er2);
    exw2_k<<<NB_E, 256, 0, stream>>>(csr_src, csr_dst, el2, er2, exw2);
    gather2_k<<<N_NODES / 4, 256, 0, stream>>>(rowp, csr_src, exw2, ft2b, out);
}